// Round 12
// baseline (251.047 us; speedup 1.0000x reference)
//
#include <hip/hip_runtime.h>
#include <hip/hip_fp16.h>

#define THREADS 320
#define IMGS 4

// s_w (fp32): c1b[0..5], group biases [6..9]
#define O_C1B 0
#define O_GB  6

// p1 fp16 layout (uint units): ch stride mod32=9, img stride mod32=22
#define P1_CHU 105
#define P1_IMGU 630
// p2 fp16: 200 uints/img (400 halves), 16B-aligned, img bank phase mod32=8
#define P2_IMGU 200
// c5 fp16: 60 uints/img (120 halves), 16B-aligned, img bank phase mod32=28
#define C5_IMGU 60

typedef _Float16 h2 __attribute__((ext_vector_type(2)));

__device__ __forceinline__ float fdot2(uint a, uint b, float c) {
    return __builtin_amdgcn_fdot2(__builtin_bit_cast(h2, a), __builtin_bit_cast(h2, b), c, false);
}
__device__ __forceinline__ uint pkh2(float a, float b) {
    return __builtin_bit_cast(uint, __builtin_amdgcn_cvt_pkrtz(a, b));
}
__device__ __forceinline__ ushort f16rn(float a) {
    _Float16 h = (_Float16)a;
    return __builtin_bit_cast(ushort, h);
}
__device__ __forceinline__ float h2lo(uint w){ return (float)__builtin_bit_cast(h2, w).x; }
__device__ __forceinline__ float h2hi(uint w){ return (float)__builtin_bit_cast(h2, w).y; }

// packed f16 fma: v_pk_fma_f16 (2 MAC/inst)
__device__ __forceinline__ uint hfma2u(uint a, uint b, uint c) {
    __half2 r = __hfma2(__builtin_bit_cast(__half2, a),
                        __builtin_bit_cast(__half2, b),
                        __builtin_bit_cast(__half2, c));
    return __builtin_bit_cast(uint, r);
}

// (hi:lo) >> 16 -> one v_alignbit_b32
__device__ __forceinline__ uint funnel16(uint hi, uint lo) {
    return __builtin_amdgcn_alignbit(hi, lo, 16);
}

__device__ __forceinline__ float fast_tanh(float v) {
    float e = __expf(2.f * v);
    return 1.f - __fdividef(2.f, e + 1.f);
}

// load one 8-half row: q = 4 aligned pairs, s = shifted-by-1 pairs (s3=(h7,0))
__device__ __forceinline__ void ld_row8(const uint* p, uint* q, uint* s) {
    uint a = p[0], b = p[1], c = p[2], d = p[3];
    q[0]=a; q[1]=b; q[2]=c; q[3]=d;
    s[0] = funnel16(b, a);
    s[1] = funnel16(c, b);
    s[2] = funnel16(d, c);
    s[3] = d >> 16;
}
// 6-half row for stage 3 (q0..q2, s0..s2)
__device__ __forceinline__ void ld_row6(const uint* p, uint* q, uint* s) {
    uint a = p[0], b = p[1], c = p[2];
    q[0]=a; q[1]=b; q[2]=c;
    s[0] = funnel16(b, a);
    s[1] = funnel16(c, b);
    s[2] = c >> 16;
}

// grouped-C3 tables
__device__ __forceinline__ int g3_ncin(int o){ return o<6?3:(o<15?4:6); }
__device__ __forceinline__ int g3_slot(int o,int j){
    return o<6 ? 6+j : (o<12 ? 9+j : (o<15 ? 13+j : 17+j));
}
__device__ __forceinline__ int g3_bi(int o){ return o<6?0:(o<12?1:(o<15?2:3)); }
__device__ __forceinline__ int g3_ch(int o,int j){
    if (o<6)  return (o+j)%6;
    if (o<12) return (o-6+j)%6;
    if (o<15) return (o-12 + j + (j>=2?1:0))%6;
    return j;
}

// pre-kernel: convert c5_w / f6_w to fp16 in workspace (RN)
__global__ __launch_bounds__(256)
void cvt_w16(const float* __restrict__ c5w, const float* __restrict__ f6w,
             ushort* __restrict__ ws) {
    int i = blockIdx.x * 256 + threadIdx.x;
    if (i < 48000) ws[i] = f16rn(c5w[i]);
    if (i < 10080) ws[48000 + i] = f16rn(f6w[i]);
}

template<bool H>
__global__ __launch_bounds__(THREADS)
void lenet_fused(const float* __restrict__ x,
                 const float* __restrict__ c1_w, const float* __restrict__ c1_b,
                 const float* __restrict__ fs_w, const float* __restrict__ fs_b,
                 const float* __restrict__ sc_w, const float* __restrict__ sc_b,
                 const float* __restrict__ th_w, const float* __restrict__ th_b,
                 const float* __restrict__ fo_w, const float* __restrict__ fo_b,
                 const float* __restrict__ c5_w, const float* __restrict__ c5_b,
                 const float* __restrict__ f6_w, const float* __restrict__ f6_b,
                 const float* __restrict__ out_w, const float* __restrict__ out_b,
                 const ushort* __restrict__ wsh,
                 float* __restrict__ out)
{
    __shared__ uint  s_p1h[IMGS * P1_IMGU];   // 10080 B; f6 (fp32) aliases after stage 4
    __shared__ uint  s_whu[23 * 16];          // 1472 B packed fp16 conv weights (pairs)
    __shared__ uint  s_wd[23 * 26];           // 2392 B dup'd pk weights (w,w) per tap
    __shared__ float s_w[10];                 // fp32 biases (c1b, group)
    __shared__ uint  s_bh[102];               // fp16 biases: c5b [0..59], f6b [60..101]
    __shared__ uint  s_u[IMGS * 512];         // 8192 B union:
                                              //  stages 1-2: x fp16 (2048 uints)
                                              //  stages 3-5: p2h [0..799], c5h [800..1039]
    uint*  s_xh  = s_u;
    uint*  s_c5u = s_u + IMGS * P2_IMGU;
    float* s_f6  = (float*)s_p1h;

    const int tid = threadIdx.x;
    const int blk = blockIdx.x;

    // ---- stage 0a: biases -> LDS ----
    if (tid < 6)  s_w[O_C1B + tid] = c1_b[tid];
    if (tid == 0){ s_w[O_GB+0]=fs_b[0]; s_w[O_GB+1]=sc_b[0]; s_w[O_GB+2]=th_b[0]; s_w[O_GB+3]=fo_b[0]; }
    if (tid < 60) s_bh[tid]      = pkh2(c5_b[2*tid], c5_b[2*tid+1]);
    if (tid < 42) s_bh[60 + tid] = pkh2(f6_b[2*tid], f6_b[2*tid+1]);

    // ---- stage 0b: conv weights -> packed fp16 (pairs) + dup'd pk form ----
    if (tid < 23) {
        const float* src;
        if      (tid < 6)  src = c1_w + tid*25;
        else if (tid < 9)  src = fs_w + (tid-6)*25;
        else if (tid < 13) src = sc_w + (tid-9)*25;
        else if (tid < 17) src = th_w + (tid-13)*25;
        else               src = fo_w + (tid-17)*25;
        uint* dst = s_whu + tid*16;
        #pragma unroll
        for (int ky=0; ky<5; ky++) {
            dst[ky*3+0] = pkh2(src[ky*5+0], src[ky*5+1]);
            dst[ky*3+1] = pkh2(src[ky*5+2], src[ky*5+3]);
            dst[ky*3+2] = pkh2(src[ky*5+4], 0.f);
        }
        uint* dd = s_wd + tid*26;
        #pragma unroll
        for (int t=0; t<25; t++) {
            float v = src[t];
            dd[t] = pkh2(v, v);
        }
    }

    // ---- stage 1: x -> LDS as fp16 pairs ----
    {
        const float4* xg = (const float4*)(x + (size_t)blk*(IMGS*1024));
        uint2* sx = (uint2*)s_u;
        #pragma unroll
        for (int i=0;i<4;i++) {
            const int id = tid + i*THREADS;
            if (id < IMGS*256) {
                float4 v = xg[id];
                sx[id] = make_uint2(pkh2(v.x,v.y), pkh2(v.z,v.w));
            }
        }
    }
    __syncthreads();

    // ---- stage 2: conv1 + tanh + 2x2 avgpool -> s_p1h (fp16) ----
    // one thread = (img, c, pw-pair): 8-wide register window, 2 pooled cols
    if (tid < IMGS*42) {
        const int img = tid/42, r2 = tid%42, c = r2/7, pq = r2%7;
        const uint* xim = s_xh + img*512 + 2*pq;   // row stride 16 uints
        uint wp[5][3];
        #pragma unroll
        for (int k=0;k<15;k++) ((uint*)wp)[k] = s_whu[c*16 + k];
        const float bias = s_w[O_C1B + c];
        uint q[6][4], s[6][4];
        #pragma unroll
        for (int r=0;r<4;r++) ld_row8(xim + r*16, q[r], s[r]);
        uint* p1o = s_p1h + img*P1_IMGU + c*P1_CHU + pq;   // uint units, ph stride 7
        #pragma unroll
        for (int ph=0; ph<14; ph++) {
            ld_row8(xim + (2*ph+4)*16, q[(2*ph+4)%6], s[(2*ph+4)%6]);
            ld_row8(xim + (2*ph+5)*16, q[(2*ph+5)%6], s[(2*ph+5)%6]);
            float sum0 = 0.f, sum1 = 0.f;
            #pragma unroll
            for (int dy=0; dy<2; dy++) {
                float t0 = bias, t1 = bias, u0 = bias, u1 = bias;
                #pragma unroll
                for (int ky=0; ky<5; ky++) {
                    const int sl = (2*ph+dy+ky)%6;
                    const uint* Q = q[sl];
                    const uint* S = s[sl];
                    t0 = fdot2(Q[2], wp[ky][2], fdot2(Q[1], wp[ky][1], fdot2(Q[0], wp[ky][0], t0)));
                    t1 = fdot2(S[2], wp[ky][2], fdot2(S[1], wp[ky][1], fdot2(S[0], wp[ky][0], t1)));
                    u0 = fdot2(Q[3], wp[ky][2], fdot2(Q[2], wp[ky][1], fdot2(Q[1], wp[ky][0], u0)));
                    u1 = fdot2(S[3], wp[ky][2], fdot2(S[2], wp[ky][1], fdot2(S[1], wp[ky][0], u1)));
                }
                sum0 += fast_tanh(t0) + fast_tanh(t1);
                sum1 += fast_tanh(u0) + fast_tanh(u1);
            }
            p1o[ph*7] = pkh2(0.25f*sum0, 0.25f*sum1);
        }
    }
    __syncthreads();

    // ---- stage 3: grouped C3 via v_pk_fma_f16 + tanh + 2x2 avgpool -> p2 fp16 ----
    // 320 items = 320 threads, single full pass; o-major (uniform trips per wave)
    {
        const int idx = tid;
        const int o = idx/(IMGS*5), r2 = idx%(IMGS*5), img = r2/5, pw = r2%5;
        const int ncin = g3_ncin(o);
        const float bias = s_w[O_GB + g3_bi(o)];
        float acc0[10], acc1[10];
        #pragma unroll
        for (int h=0;h<10;h++){ acc0[h]=bias; acc1[h]=bias; }
        for (int j=0;j<ncin;j++) {
            const uint* p1c = s_p1h + img*P1_IMGU + g3_ch(o,j)*P1_CHU + pw;
            const int slot = g3_slot(o,j);
            uint wd[25];
            #pragma unroll
            for (int t=0;t<25;t++) wd[t] = s_wd[slot*26 + t];
            uint accp[10];
            #pragma unroll
            for (int h=0;h<10;h++) accp[h] = 0u;
            #pragma unroll
            for (int r=0;r<14;r++) {
                uint P[5], S3[3];
                ld_row6(p1c + r*7, P, S3);
                const uint P0=P[0], P2=P[1], P4=P[2];
                const uint P1=S3[0], P3=S3[1];
                #pragma unroll
                for (int ky=0;ky<5;ky++) {
                    const int hh = r - ky;
                    if (hh >= 0 && hh < 10) {
                        accp[hh] = hfma2u(P0, wd[ky*5+0], accp[hh]);
                        accp[hh] = hfma2u(P1, wd[ky*5+1], accp[hh]);
                        accp[hh] = hfma2u(P2, wd[ky*5+2], accp[hh]);
                        accp[hh] = hfma2u(P3, wd[ky*5+3], accp[hh]);
                        accp[hh] = hfma2u(P4, wd[ky*5+4], accp[hh]);
                    }
                }
            }
            #pragma unroll
            for (int h=0;h<10;h++) {
                acc0[h] += h2lo(accp[h]);
                acc1[h] += h2hi(accp[h]);
            }
        }
        ushort* p2o = (ushort*)s_u + img*(P2_IMGU*2) + o*25 + pw;
        #pragma unroll
        for (int ph=0; ph<5; ph++) {
            float t = fast_tanh(acc0[2*ph])   + fast_tanh(acc1[2*ph])
                    + fast_tanh(acc0[2*ph+1]) + fast_tanh(acc1[2*ph+1]);
            p2o[ph*5] = f16rn(0.25f*t);
        }
    }
    __syncthreads();

    // ---- stage 4: conv5 = 120x400 matvec + tanh -> c5 fp16 (b128 LDS reads) ----
    #pragma unroll
    for (int it=0; it<2; it++) {
        const int id2 = tid + THREADS*it;
        if (id2 < 120*IMGS) {
            const int f = id2 >> 2, img = id2 & 3;
            const uint4* pr4 = (const uint4*)(s_u + img * P2_IMGU);  // 16B aligned
            float a0=0.f, a1=0.f, a2=0.f, a3=0.f;
            if constexpr (H) {
                const uint4* wr = (const uint4*)(wsh + f*400);   // 50 x uint4 = 400 halves
                #pragma unroll 5
                for (int k=0;k<50;k++) {
                    uint4 w4 = wr[k];
                    uint4 p4 = pr4[k];
                    a0 = fdot2(p4.x, w4.x, a0);
                    a1 = fdot2(p4.y, w4.y, a1);
                    a2 = fdot2(p4.z, w4.z, a2);
                    a3 = fdot2(p4.w, w4.w, a3);
                }
            } else {
                const float4* wr = (const float4*)(c5_w + f*400);
                #pragma unroll 2
                for (int k=0;k<50;k++) {
                    float4 wa = wr[2*k], wb = wr[2*k+1];
                    uint4 p4 = pr4[k];
                    h2 h0 = __builtin_bit_cast(h2, p4.x);
                    h2 h1 = __builtin_bit_cast(h2, p4.y);
                    h2 h2v = __builtin_bit_cast(h2, p4.z);
                    h2 h3 = __builtin_bit_cast(h2, p4.w);
                    a0 = fmaf((float)h0.x, wa.x, a0); a1 = fmaf((float)h0.y, wa.y, a1);
                    a2 = fmaf((float)h1.x, wa.z, a2); a3 = fmaf((float)h1.y, wa.w, a3);
                    a0 = fmaf((float)h2v.x, wb.x, a0); a1 = fmaf((float)h2v.y, wb.y, a1);
                    a2 = fmaf((float)h3.x, wb.z, a2); a3 = fmaf((float)h3.y, wb.w, a3);
                }
            }
            const uint bw = s_bh[f >> 1];
            const float bias = (f & 1) ? h2hi(bw) : h2lo(bw);
            ((ushort*)s_c5u)[img*(C5_IMGU*2) + f] =
                f16rn(fast_tanh((a0+a1)+(a2+a3) + bias));
        }
    }
    __syncthreads();

    // ---- stage 5: f6 (84x120) + tanh -> s_f6 fp32 (aliases dead p1) ----
    #pragma unroll
    for (int it=0; it<2; it++) {
        const int id2 = tid + THREADS*it;
        if (id2 < 84*IMGS) {
            const int j = id2 >> 2, img = id2 & 3;
            const uint4* cr4 = (const uint4*)(s_c5u + img * C5_IMGU);  // 16B aligned
            float a0=0.f, a1=0.f, a2=0.f, a3=0.f;
            if constexpr (H) {
                const uint4* wr = (const uint4*)(wsh + 48000 + j*120); // 15 x uint4
                #pragma unroll
                for (int k=0;k<15;k++) {
                    uint4 w4 = wr[k];
                    uint4 c4 = cr4[k];
                    a0 = fdot2(c4.x, w4.x, a0);
                    a1 = fdot2(c4.y, w4.y, a1);
                    a2 = fdot2(c4.z, w4.z, a2);
                    a3 = fdot2(c4.w, w4.w, a3);
                }
            } else {
                const float4* wr = (const float4*)(f6_w + j*120);
                #pragma unroll
                for (int k=0;k<15;k++) {
                    float4 wa = wr[2*k], wb = wr[2*k+1];
                    uint4 c4 = cr4[k];
                    h2 h0 = __builtin_bit_cast(h2, c4.x);
                    h2 h1 = __builtin_bit_cast(h2, c4.y);
                    h2 h2v = __builtin_bit_cast(h2, c4.z);
                    h2 h3 = __builtin_bit_cast(h2, c4.w);
                    a0 = fmaf((float)h0.x, wa.x, a0); a1 = fmaf((float)h0.y, wa.y, a1);
                    a2 = fmaf((float)h1.x, wa.z, a2); a3 = fmaf((float)h1.y, wa.w, a3);
                    a0 = fmaf((float)h2v.x, wb.x, a0); a1 = fmaf((float)h2v.y, wb.y, a1);
                    a2 = fmaf((float)h3.x, wb.z, a2); a3 = fmaf((float)h3.y, wb.w, a3);
                }
            }
            const uint bw = s_bh[60 + (j >> 1)];
            const float bias = (j & 1) ? h2hi(bw) : h2lo(bw);
            s_f6[img*84 + j] = fast_tanh((a0+a1)+(a2+a3) + bias);
        }
    }
    __syncthreads();

    // ---- stage 6: out (10x84) -> global ----
    if (tid < 10*IMGS) {
        const int j = tid >> 2, img = tid & 3;
        const float* wr = out_w + j*84;
        const float* fr = s_f6 + img*84;
        float a0=0.f,a1=0.f,a2=0.f,a3=0.f;
        #pragma unroll
        for (int k=0;k<84;k+=4) {
            a0=fmaf(wr[k],  fr[k],  a0); a1=fmaf(wr[k+1],fr[k+1],a1);
            a2=fmaf(wr[k+2],fr[k+2],a2); a3=fmaf(wr[k+3],fr[k+3],a3);
        }
        out[((size_t)blk*IMGS + img)*10 + j] = (a0+a1)+(a2+a3) + out_b[j];
    }
}

extern "C" void kernel_launch(void* const* d_in, const int* in_sizes, int n_in,
                              void* d_out, int out_size, void* d_ws, size_t ws_size,
                              hipStream_t stream) {
    const float* x    = (const float*)d_in[0];
    const float* c1w  = (const float*)d_in[1];
    const float* c1b  = (const float*)d_in[2];
    const float* fsw  = (const float*)d_in[3];
    const float* fsb  = (const float*)d_in[4];
    const float* scw  = (const float*)d_in[5];
    const float* scb  = (const float*)d_in[6];
    const float* thw  = (const float*)d_in[7];
    const float* thb  = (const float*)d_in[8];
    const float* fow  = (const float*)d_in[9];
    const float* fob  = (const float*)d_in[10];
    const float* c5w  = (const float*)d_in[11];
    const float* c5b  = (const float*)d_in[12];
    const float* f6w  = (const float*)d_in[13];
    const float* f6b  = (const float*)d_in[14];
    const float* outw = (const float*)d_in[15];
    const float* outb = (const float*)d_in[16];
    float* outp = (float*)d_out;

    const int B = in_sizes[0] / 1024;     // 16384
    const int nblk = B / IMGS;            // 4096
    const size_t ws_need = (48000 + 10080) * sizeof(ushort);

    if (ws_size >= ws_need) {
        ushort* wsh = (ushort*)d_ws;
        cvt_w16<<<188, 256, 0, stream>>>(c5w, f6w, wsh);
        lenet_fused<true><<<nblk, THREADS, 0, stream>>>(
            x, c1w, c1b, fsw, fsb, scw, scb, thw, thb, fow, fob,
            c5w, c5b, f6w, f6b, outw, outb, wsh, outp);
    } else {
        lenet_fused<false><<<nblk, THREADS, 0, stream>>>(
            x, c1w, c1b, fsw, fsb, scw, scb, thw, thb, fow, fob,
            c5w, c5b, f6w, f6b, outw, outb, (const ushort*)nullptr, outp);
    }
}

// Round 13
// 195.820 us; speedup vs baseline: 1.2820x; 1.2820x over previous
//
#include <hip/hip_runtime.h>
#include <hip/hip_fp16.h>

#define THREADS 256
#define IMGS 4

// s_w (fp32): c1b[0..5], group biases [6..9]
#define O_C1B 0
#define O_GB  6

// p1 fp16 layout (uint units): ch stride mod32=9, img stride mod32=22
#define P1_CHU 105
#define P1_IMGU 630
// p2 fp16: 200 uints/img (400 halves), 16B-aligned, img bank phase mod32=8
#define P2_IMGU 200
// c5 fp16: 60 uints/img (120 halves), 16B-aligned, img bank phase mod32=28
#define C5_IMGU 60

typedef _Float16 h2 __attribute__((ext_vector_type(2)));

__device__ __forceinline__ float fdot2(uint a, uint b, float c) {
    return __builtin_amdgcn_fdot2(__builtin_bit_cast(h2, a), __builtin_bit_cast(h2, b), c, false);
}
__device__ __forceinline__ uint pkh2(float a, float b) {
    return __builtin_bit_cast(uint, __builtin_amdgcn_cvt_pkrtz(a, b));
}
__device__ __forceinline__ ushort f16rn(float a) {
    _Float16 h = (_Float16)a;
    return __builtin_bit_cast(ushort, h);
}
__device__ __forceinline__ float h2lo(uint w){ return (float)__builtin_bit_cast(h2, w).x; }
__device__ __forceinline__ float h2hi(uint w){ return (float)__builtin_bit_cast(h2, w).y; }

// packed f16 fma: v_pk_fma_f16 (2 MAC/inst)
__device__ __forceinline__ uint hfma2u(uint a, uint b, uint c) {
    __half2 r = __hfma2(__builtin_bit_cast(__half2, a),
                        __builtin_bit_cast(__half2, b),
                        __builtin_bit_cast(__half2, c));
    return __builtin_bit_cast(uint, r);
}

// (hi:lo) >> 16 -> one v_alignbit_b32
__device__ __forceinline__ uint funnel16(uint hi, uint lo) {
    return __builtin_amdgcn_alignbit(hi, lo, 16);
}

__device__ __forceinline__ float fast_tanh(float v) {
    float e = __expf(2.f * v);
    return 1.f - __fdividef(2.f, e + 1.f);
}

// load one 6-half row: q = aligned pairs, s = shifted-by-1 pairs
__device__ __forceinline__ void ld_row(const uint* p, uint* q, uint* s) {
    uint a = p[0], b = p[1], c = p[2];
    q[0] = a; q[1] = b; q[2] = c;
    s[0] = funnel16(b, a);
    s[1] = funnel16(c, b);
    s[2] = c >> 16;
}

// grouped-C3 tables
__device__ __forceinline__ int g3_ncin(int o){ return o<6?3:(o<15?4:6); }
__device__ __forceinline__ int g3_slot(int o,int j){
    return o<6 ? 6+j : (o<12 ? 9+j : (o<15 ? 13+j : 17+j));
}
__device__ __forceinline__ int g3_bi(int o){ return o<6?0:(o<12?1:(o<15?2:3)); }
__device__ __forceinline__ int g3_ch(int o,int j){
    if (o<6)  return (o+j)%6;
    if (o<12) return (o-6+j)%6;
    if (o<15) return (o-12 + j + (j>=2?1:0))%6;
    return j;
}
// stage-3 position->output map: heavy outputs (o=15, o=6..14) first, light (ncin=3) tail
__device__ __forceinline__ int g3_omap(int p){
    return (p==0) ? 15 : (p<10 ? p+5 : p-10);
}

// pre-kernel: convert c5_w / f6_w to fp16 in workspace (RN)
__global__ __launch_bounds__(256)
void cvt_w16(const float* __restrict__ c5w, const float* __restrict__ f6w,
             ushort* __restrict__ ws) {
    int i = blockIdx.x * 256 + threadIdx.x;
    if (i < 48000) ws[i] = f16rn(c5w[i]);
    if (i < 10080) ws[48000 + i] = f16rn(f6w[i]);
}

template<bool H>
__global__ __launch_bounds__(THREADS)
void lenet_fused(const float* __restrict__ x,
                 const float* __restrict__ c1_w, const float* __restrict__ c1_b,
                 const float* __restrict__ fs_w, const float* __restrict__ fs_b,
                 const float* __restrict__ sc_w, const float* __restrict__ sc_b,
                 const float* __restrict__ th_w, const float* __restrict__ th_b,
                 const float* __restrict__ fo_w, const float* __restrict__ fo_b,
                 const float* __restrict__ c5_w, const float* __restrict__ c5_b,
                 const float* __restrict__ f6_w, const float* __restrict__ f6_b,
                 const float* __restrict__ out_w, const float* __restrict__ out_b,
                 const ushort* __restrict__ wsh,
                 float* __restrict__ out)
{
    __shared__ uint  s_p1h[IMGS * P1_IMGU];   // 10080 B; f6 (fp32) aliases after stage 4
    __shared__ uint  s_whu[23 * 16];          // 1472 B packed fp16 conv weights (pairs)
    __shared__ uint  s_wd[23 * 26];           // 2392 B dup'd pk weights (w,w) per tap
    __shared__ float s_w[10];                 // fp32 biases (c1b, group)
    __shared__ uint  s_bh[102];               // fp16 biases: c5b [0..59], f6b [60..101]
    __shared__ uint  s_u[IMGS * 512];         // 8192 B union:
                                              //  stages 1-2: x fp16 (2048 uints)
                                              //  stages 3-5: p2h [0..799], c5h [800..1039]
    uint*  s_xh  = s_u;
    uint*  s_c5u = s_u + IMGS * P2_IMGU;
    float* s_f6  = (float*)s_p1h;

    const int tid = threadIdx.x;
    const int blk = blockIdx.x;

    // ---- stage 0a: biases -> LDS ----
    if (tid < 6)  s_w[O_C1B + tid] = c1_b[tid];
    if (tid == 0){ s_w[O_GB+0]=fs_b[0]; s_w[O_GB+1]=sc_b[0]; s_w[O_GB+2]=th_b[0]; s_w[O_GB+3]=fo_b[0]; }
    if (tid < 60) s_bh[tid]      = pkh2(c5_b[2*tid], c5_b[2*tid+1]);
    if (tid < 42) s_bh[60 + tid] = pkh2(f6_b[2*tid], f6_b[2*tid+1]);

    // ---- stage 0b: conv weights -> packed fp16 (pairs) + dup'd pk form ----
    if (tid < 23) {
        const float* src;
        if      (tid < 6)  src = c1_w + tid*25;
        else if (tid < 9)  src = fs_w + (tid-6)*25;
        else if (tid < 13) src = sc_w + (tid-9)*25;
        else if (tid < 17) src = th_w + (tid-13)*25;
        else               src = fo_w + (tid-17)*25;
        uint* dst = s_whu + tid*16;
        #pragma unroll
        for (int ky=0; ky<5; ky++) {
            dst[ky*3+0] = pkh2(src[ky*5+0], src[ky*5+1]);
            dst[ky*3+1] = pkh2(src[ky*5+2], src[ky*5+3]);
            dst[ky*3+2] = pkh2(src[ky*5+4], 0.f);
        }
        uint* dd = s_wd + tid*26;
        #pragma unroll
        for (int t=0; t<25; t++) {
            float v = src[t];
            dd[t] = pkh2(v, v);
        }
    }

    // ---- stage 1: x -> LDS as fp16 pairs ----
    {
        const float4* xg = (const float4*)(x + (size_t)blk*(IMGS*1024));
        uint2* sx = (uint2*)s_u;
        #pragma unroll
        for (int i=0;i<(IMGS*1024/4)/THREADS;i++) {
            float4 v = xg[tid + i*THREADS];
            sx[tid + i*THREADS] = make_uint2(pkh2(v.x,v.y), pkh2(v.z,v.w));
        }
    }
    __syncthreads();

    // ---- stage 2: conv1 + tanh + 2x2 avgpool -> s_p1h (fp16) ----
    for (int idx=tid; idx<IMGS*84; idx+=THREADS) {
        const int img = idx/84, r2 = idx%84, c = r2/14, pw = r2%14;
        const uint* xim = s_xh + img*512 + pw;
        uint wp[5][3];
        #pragma unroll
        for (int k=0;k<15;k++) ((uint*)wp)[k] = s_whu[c*16 + k];
        const float bias = s_w[O_C1B + c];
        uint q[6][3], s[6][3];
        #pragma unroll
        for (int r=0;r<4;r++) ld_row(xim + r*16, q[r], s[r]);
        ushort* p1o = (ushort*)s_p1h + img*(P1_IMGU*2) + c*(P1_CHU*2) + pw;
        #pragma unroll
        for (int ph=0; ph<14; ph++) {
            ld_row(xim + (2*ph+4)*16, q[(2*ph+4)%6], s[(2*ph+4)%6]);
            ld_row(xim + (2*ph+5)*16, q[(2*ph+5)%6], s[(2*ph+5)%6]);
            float sum = 0.f;
            #pragma unroll
            for (int dy=0; dy<2; dy++)
            #pragma unroll
            for (int dx=0; dx<2; dx++) {
                float t = bias;
                #pragma unroll
                for (int ky=0; ky<5; ky++) {
                    const int sl = (2*ph+dy+ky)%6;
                    const uint* rr = dx ? s[sl] : q[sl];
                    t = fdot2(rr[0], wp[ky][0], t);
                    t = fdot2(rr[1], wp[ky][1], t);
                    t = fdot2(rr[2], wp[ky][2], t);
                }
                sum += fast_tanh(t);
            }
            p1o[ph*14] = f16rn(0.25f*sum);
        }
    }
    __syncthreads();

    // ---- stage 3: grouped C3 via v_pk_fma_f16 + tanh + 2x2 avgpool -> p2 fp16 ----
    // heavy-first omap: tail pass (64 items) gets only ncin=3 outputs
    for (int idx=tid; idx<IMGS*80; idx+=THREADS) {
        const int p = idx/(IMGS*5), r2 = idx%(IMGS*5), img = r2/5, pw = r2%5;
        const int o = g3_omap(p);
        const int ncin = g3_ncin(o);
        const float bias = s_w[O_GB + g3_bi(o)];
        float acc0[10], acc1[10];
        #pragma unroll
        for (int h=0;h<10;h++){ acc0[h]=bias; acc1[h]=bias; }
        for (int j=0;j<ncin;j++) {
            const uint* p1c = s_p1h + img*P1_IMGU + g3_ch(o,j)*P1_CHU + pw;
            const int slot = g3_slot(o,j);
            uint wd[25];
            #pragma unroll
            for (int t=0;t<25;t++) wd[t] = s_wd[slot*26 + t];
            uint accp[10];
            #pragma unroll
            for (int h=0;h<10;h++) accp[h] = 0u;
            #pragma unroll
            for (int r=0;r<14;r++) {
                uint a = p1c[r*7], b = p1c[r*7+1], cc = p1c[r*7+2];
                uint s1 = funnel16(b, a);
                uint s3 = funnel16(cc, b);
                const uint P0=a, P1=s1, P2=b, P3=s3, P4=cc;
                #pragma unroll
                for (int ky=0;ky<5;ky++) {
                    const int hh = r - ky;
                    if (hh >= 0 && hh < 10) {
                        accp[hh] = hfma2u(P0, wd[ky*5+0], accp[hh]);
                        accp[hh] = hfma2u(P1, wd[ky*5+1], accp[hh]);
                        accp[hh] = hfma2u(P2, wd[ky*5+2], accp[hh]);
                        accp[hh] = hfma2u(P3, wd[ky*5+3], accp[hh]);
                        accp[hh] = hfma2u(P4, wd[ky*5+4], accp[hh]);
                    }
                }
            }
            #pragma unroll
            for (int h=0;h<10;h++) {
                acc0[h] += h2lo(accp[h]);
                acc1[h] += h2hi(accp[h]);
            }
        }
        ushort* p2o = (ushort*)s_u + img*(P2_IMGU*2) + o*25 + pw;
        #pragma unroll
        for (int ph=0; ph<5; ph++) {
            float t = fast_tanh(acc0[2*ph])   + fast_tanh(acc1[2*ph])
                    + fast_tanh(acc0[2*ph+1]) + fast_tanh(acc1[2*ph+1]);
            p2o[ph*5] = f16rn(0.25f*t);
        }
    }
    __syncthreads();

    // ---- stage 4: conv5 = 120x400 matvec + tanh -> c5 fp16 (b128 LDS reads) ----
    #pragma unroll
    for (int it=0; it<2; it++) {
        const int id2 = tid + THREADS*it;
        if (id2 < 120*IMGS) {
            const int f = id2 >> 2, img = id2 & 3;
            const uint4* pr4 = (const uint4*)(s_u + img * P2_IMGU);  // 16B aligned
            float a0=0.f, a1=0.f, a2=0.f, a3=0.f;
            if constexpr (H) {
                const uint4* wr = (const uint4*)(wsh + f*400);   // 50 x uint4 = 400 halves
                #pragma unroll 5
                for (int k=0;k<50;k++) {
                    uint4 w4 = wr[k];
                    uint4 p4 = pr4[k];
                    a0 = fdot2(p4.x, w4.x, a0);
                    a1 = fdot2(p4.y, w4.y, a1);
                    a2 = fdot2(p4.z, w4.z, a2);
                    a3 = fdot2(p4.w, w4.w, a3);
                }
            } else {
                const float4* wr = (const float4*)(c5_w + f*400);
                #pragma unroll 2
                for (int k=0;k<50;k++) {
                    float4 wa = wr[2*k], wb = wr[2*k+1];
                    uint4 p4 = pr4[k];
                    h2 h0 = __builtin_bit_cast(h2, p4.x);
                    h2 h1 = __builtin_bit_cast(h2, p4.y);
                    h2 h2v = __builtin_bit_cast(h2, p4.z);
                    h2 h3 = __builtin_bit_cast(h2, p4.w);
                    a0 = fmaf((float)h0.x, wa.x, a0); a1 = fmaf((float)h0.y, wa.y, a1);
                    a2 = fmaf((float)h1.x, wa.z, a2); a3 = fmaf((float)h1.y, wa.w, a3);
                    a0 = fmaf((float)h2v.x, wb.x, a0); a1 = fmaf((float)h2v.y, wb.y, a1);
                    a2 = fmaf((float)h3.x, wb.z, a2); a3 = fmaf((float)h3.y, wb.w, a3);
                }
            }
            const uint bw = s_bh[f >> 1];
            const float bias = (f & 1) ? h2hi(bw) : h2lo(bw);
            ((ushort*)s_c5u)[img*(C5_IMGU*2) + f] =
                f16rn(fast_tanh((a0+a1)+(a2+a3) + bias));
        }
    }
    __syncthreads();

    // ---- stage 5: f6 (84x120) + tanh -> s_f6 fp32 (aliases dead p1) ----
    #pragma unroll
    for (int it=0; it<2; it++) {
        const int id2 = tid + THREADS*it;
        if (id2 < 84*IMGS) {
            const int j = id2 >> 2, img = id2 & 3;
            const uint4* cr4 = (const uint4*)(s_c5u + img * C5_IMGU);  // 16B aligned
            float a0=0.f, a1=0.f, a2=0.f, a3=0.f;
            if constexpr (H) {
                const uint4* wr = (const uint4*)(wsh + 48000 + j*120); // 15 x uint4
                #pragma unroll
                for (int k=0;k<15;k++) {
                    uint4 w4 = wr[k];
                    uint4 c4 = cr4[k];
                    a0 = fdot2(c4.x, w4.x, a0);
                    a1 = fdot2(c4.y, w4.y, a1);
                    a2 = fdot2(c4.z, w4.z, a2);
                    a3 = fdot2(c4.w, w4.w, a3);
                }
            } else {
                const float4* wr = (const float4*)(f6_w + j*120);
                #pragma unroll
                for (int k=0;k<15;k++) {
                    float4 wa = wr[2*k], wb = wr[2*k+1];
                    uint4 c4 = cr4[k];
                    h2 h0 = __builtin_bit_cast(h2, c4.x);
                    h2 h1 = __builtin_bit_cast(h2, c4.y);
                    h2 h2v = __builtin_bit_cast(h2, c4.z);
                    h2 h3 = __builtin_bit_cast(h2, c4.w);
                    a0 = fmaf((float)h0.x, wa.x, a0); a1 = fmaf((float)h0.y, wa.y, a1);
                    a2 = fmaf((float)h1.x, wa.z, a2); a3 = fmaf((float)h1.y, wa.w, a3);
                    a0 = fmaf((float)h2v.x, wb.x, a0); a1 = fmaf((float)h2v.y, wb.y, a1);
                    a2 = fmaf((float)h3.x, wb.z, a2); a3 = fmaf((float)h3.y, wb.w, a3);
                }
            }
            const uint bw = s_bh[60 + (j >> 1)];
            const float bias = (j & 1) ? h2hi(bw) : h2lo(bw);
            s_f6[img*84 + j] = fast_tanh((a0+a1)+(a2+a3) + bias);
        }
    }
    __syncthreads();

    // ---- stage 6: out (10x84) -> global ----
    if (tid < 10*IMGS) {
        const int j = tid >> 2, img = tid & 3;
        const float* wr = out_w + j*84;
        const float* fr = s_f6 + img*84;
        float a0=0.f,a1=0.f,a2=0.f,a3=0.f;
        #pragma unroll
        for (int k=0;k<84;k+=4) {
            a0=fmaf(wr[k],  fr[k],  a0); a1=fmaf(wr[k+1],fr[k+1],a1);
            a2=fmaf(wr[k+2],fr[k+2],a2); a3=fmaf(wr[k+3],fr[k+3],a3);
        }
        out[((size_t)blk*IMGS + img)*10 + j] = (a0+a1)+(a2+a3) + out_b[j];
    }
}

extern "C" void kernel_launch(void* const* d_in, const int* in_sizes, int n_in,
                              void* d_out, int out_size, void* d_ws, size_t ws_size,
                              hipStream_t stream) {
    const float* x    = (const float*)d_in[0];
    const float* c1w  = (const float*)d_in[1];
    const float* c1b  = (const float*)d_in[2];
    const float* fsw  = (const float*)d_in[3];
    const float* fsb  = (const float*)d_in[4];
    const float* scw  = (const float*)d_in[5];
    const float* scb  = (const float*)d_in[6];
    const float* thw  = (const float*)d_in[7];
    const float* thb  = (const float*)d_in[8];
    const float* fow  = (const float*)d_in[9];
    const float* fob  = (const float*)d_in[10];
    const float* c5w  = (const float*)d_in[11];
    const float* c5b  = (const float*)d_in[12];
    const float* f6w  = (const float*)d_in[13];
    const float* f6b  = (const float*)d_in[14];
    const float* outw = (const float*)d_in[15];
    const float* outb = (const float*)d_in[16];
    float* outp = (float*)d_out;

    const int B = in_sizes[0] / 1024;     // 16384
    const int nblk = B / IMGS;            // 4096
    const size_t ws_need = (48000 + 10080) * sizeof(ushort);

    if (ws_size >= ws_need) {
        ushort* wsh = (ushort*)d_ws;
        cvt_w16<<<188, 256, 0, stream>>>(c5w, f6w, wsh);
        lenet_fused<true><<<nblk, THREADS, 0, stream>>>(
            x, c1w, c1b, fsw, fsb, scw, scb, thw, thb, fow, fob,
            c5w, c5b, f6w, f6b, outw, outb, wsh, outp);
    } else {
        lenet_fused<false><<<nblk, THREADS, 0, stream>>>(
            x, c1w, c1b, fsw, fsb, scw, scb, thw, thb, fow, fob,
            c5w, c5b, f6w, f6b, outw, outb, (const ushort*)nullptr, outp);
    }
}

// Round 14
// 185.047 us; speedup vs baseline: 1.3567x; 1.0582x over previous
//
#include <hip/hip_runtime.h>
#include <hip/hip_fp16.h>

#define THREADS 256
#define IMGS 4

// s_w (fp32): c1b[0..5], group biases [6..9]
#define O_C1B 0
#define O_GB  6

// p1 fp16 layout (uint units): ch stride mod32=9, img stride mod32=22
#define P1_CHU 105
#define P1_IMGU 630
// p2 fp16: 200 uints/img (400 halves), 16B-aligned
#define P2_IMGU 200
// c5 fp16: 60 uints/img (120 halves), 16B-aligned
#define C5_IMGU 60

typedef _Float16 h2 __attribute__((ext_vector_type(2)));
typedef _Float16 h8 __attribute__((ext_vector_type(8)));
typedef float    f32x4 __attribute__((ext_vector_type(4)));
typedef uint     u32x4 __attribute__((ext_vector_type(4)));

__device__ __forceinline__ float fdot2(uint a, uint b, float c) {
    return __builtin_amdgcn_fdot2(__builtin_bit_cast(h2, a), __builtin_bit_cast(h2, b), c, false);
}
__device__ __forceinline__ uint pkh2(float a, float b) {
    return __builtin_bit_cast(uint, __builtin_amdgcn_cvt_pkrtz(a, b));
}
__device__ __forceinline__ ushort f16rn(float a) {
    _Float16 h = (_Float16)a;
    return __builtin_bit_cast(ushort, h);
}
__device__ __forceinline__ float h2lo(uint w){ return (float)__builtin_bit_cast(h2, w).x; }
__device__ __forceinline__ float h2hi(uint w){ return (float)__builtin_bit_cast(h2, w).y; }

// combine two zero-extended u16 values into packed (lo, hi): one v_perm_b32
__device__ __forceinline__ uint pair16(uint hi, uint lo) {
    return __builtin_amdgcn_perm(hi, lo, 0x05040100u);
}
// (hi:lo) >> 16 -> one v_alignbit_b32
__device__ __forceinline__ uint funnel16(uint hi, uint lo) {
    return __builtin_amdgcn_alignbit(hi, lo, 16);
}

__device__ __forceinline__ float fast_tanh(float v) {
    float e = __expf(2.f * v);
    return 1.f - __fdividef(2.f, e + 1.f);
}

// load one 6-half row: q = aligned pairs, s = shifted-by-1 pairs
__device__ __forceinline__ void ld_row(const uint* p, uint* q, uint* s) {
    uint a = p[0], b = p[1], c = p[2];
    q[0] = a; q[1] = b; q[2] = c;
    s[0] = funnel16(b, a);
    s[1] = funnel16(c, b);
    s[2] = c >> 16;
}

// pre-kernel: convert c5_w / f6_w to fp16 in workspace (RN)
__global__ __launch_bounds__(256)
void cvt_w16(const float* __restrict__ c5w, const float* __restrict__ f6w,
             ushort* __restrict__ ws) {
    int i = blockIdx.x * 256 + threadIdx.x;
    if (i < 48000) ws[i] = f16rn(c5w[i]);
    if (i < 10080) ws[48000 + i] = f16rn(f6w[i]);
}

template<bool H>
__global__ __launch_bounds__(THREADS)
void lenet_fused(const float* __restrict__ x,
                 const float* __restrict__ c1_w, const float* __restrict__ c1_b,
                 const float* __restrict__ fs_w, const float* __restrict__ fs_b,
                 const float* __restrict__ sc_w, const float* __restrict__ sc_b,
                 const float* __restrict__ th_w, const float* __restrict__ th_b,
                 const float* __restrict__ fo_w, const float* __restrict__ fo_b,
                 const float* __restrict__ c5_w, const float* __restrict__ c5_b,
                 const float* __restrict__ f6_w, const float* __restrict__ f6_b,
                 const float* __restrict__ out_w, const float* __restrict__ out_b,
                 const ushort* __restrict__ wsh,
                 float* __restrict__ out)
{
    __shared__ uint   s_p1h[IMGS * P1_IMGU];  // 10080 B; f6 (fp32) aliases after stage 4
    __shared__ uint   s_whu[6 * 16];          // conv1 fp16 pair weights
    __shared__ float  s_w[10];                // fp32 biases (c1b + group, c1b used)
    __shared__ float  s_gb16[16];             // per-o group bias for stage 3
    __shared__ uint   s_bh[102];              // fp16 biases: c5b [0..59], f6b [60..101]
    __shared__ ushort s_At[160*16];           // 5120 B  A matrix [k][o] f16 (zero-padded grouping)
    __shared__ ushort s_cb[400];              // col -> p1 half-index base (img,h,w)
    __shared__ uint   s_offs[80];             // packed tap offsets (2 u16 per uint)
    __shared__ ushort s_qd[100];              // quad -> p2 dest half-base
    __shared__ uint   s_u[IMGS * 512];        // 8192 B union: x fp16 / p2h+c5h
    uint*  s_xh  = s_u;
    uint*  s_c5u = s_u + IMGS * P2_IMGU;
    float* s_f6  = (float*)s_p1h;

    const int tid = threadIdx.x;
    const int blk = blockIdx.x;

    // ---- stage 0a: biases -> LDS ----
    if (tid < 6)  s_w[O_C1B + tid] = c1_b[tid];
    if (tid == 0){ s_w[O_GB+0]=fs_b[0]; s_w[O_GB+1]=sc_b[0]; s_w[O_GB+2]=th_b[0]; s_w[O_GB+3]=fo_b[0]; }
    if (tid < 16) s_gb16[tid] = tid<6 ? fs_b[0] : (tid<12 ? sc_b[0] : (tid<15 ? th_b[0] : fo_b[0]));
    if (tid < 60) s_bh[tid]      = pkh2(c5_b[2*tid], c5_b[2*tid+1]);
    if (tid < 42) s_bh[60 + tid] = pkh2(f6_b[2*tid], f6_b[2*tid+1]);

    // ---- stage 0b: conv1 weights -> packed fp16 pairs ----
    if (tid < 6) {
        const float* src = c1_w + tid*25;
        uint* dst = s_whu + tid*16;
        #pragma unroll
        for (int ky=0; ky<5; ky++) {
            dst[ky*3+0] = pkh2(src[ky*5+0], src[ky*5+1]);
            dst[ky*3+1] = pkh2(src[ky*5+2], src[ky*5+3]);
            dst[ky*3+2] = pkh2(src[ky*5+4], 0.f);
        }
    }

    // ---- stage 0c: MFMA tables ----
    // A matrix [k=160][o=16] f16, zero-padded grouped weights
    for (int e = tid; e < 2560; e += THREADS) {
        const int t = e >> 4, o = e & 15;
        float v = 0.f;
        if (t < 150) {
            const int ch = t / 25, tap = t % 25;
            if (o < 6)       { int d = ch - o;      if (d < 0) d += 6; if (d < 3) v = fs_w[d*25 + tap]; }
            else if (o < 12) { int d = ch - (o-6);  if (d < 0) d += 6; if (d < 4) v = sc_w[d*25 + tap]; }
            else if (o < 15) { int d = ch - (o-12); if (d < 0) d += 6;
                               int j = (d<2) ? d : (d==3 ? 2 : (d==4 ? 3 : -1));
                               if (j >= 0) v = th_w[j*25 + tap]; }
            else             v = fo_w[ch*25 + tap];
        }
        s_At[t*16 + o] = f16rn(v);
    }
    // col -> p1 base: col = quad*4 + corner; quad = img*25 + qh*5 + qw
    for (int col = tid; col < 400; col += THREADS) {
        const int Q = col >> 2, corner = col & 3;
        const int img = Q / 25, q = Q % 25;
        const int qh = q / 5, qw = q % 5;
        const int h = 2*qh + (corner & 1);
        const int w = 2*qw + (corner >> 1);
        s_cb[col] = (ushort)(img*(P1_IMGU*2) + h*14 + w);
    }
    // packed tap offsets (within p1, half units); taps >=150 -> 0 (A is zero there)
    for (int i = tid; i < 80; i += THREADS) {
        uint o2[2];
        #pragma unroll
        for (int z=0; z<2; z++) {
            const int t = 2*i + z;
            if (t < 150) {
                const int ch = t/25, rem = t%25, ky = rem/5, kx = rem%5;
                o2[z] = (uint)(ch*(P1_CHU*2) + ky*14 + kx);
            } else o2[z] = 0u;
        }
        s_offs[i] = o2[0] | (o2[1] << 16);
    }
    // quad -> p2 dest half-base
    for (int Q = tid; Q < 100; Q += THREADS) {
        s_qd[Q] = (ushort)((Q/25)*(P2_IMGU*2) + (Q%25));
    }

    // ---- stage 1: x -> LDS as fp16 pairs ----
    {
        const float4* xg = (const float4*)(x + (size_t)blk*(IMGS*1024));
        uint2* sx = (uint2*)s_u;
        #pragma unroll
        for (int i=0;i<(IMGS*1024/4)/THREADS;i++) {
            float4 v = xg[tid + i*THREADS];
            sx[tid + i*THREADS] = make_uint2(pkh2(v.x,v.y), pkh2(v.z,v.w));
        }
    }
    __syncthreads();

    // ---- stage 2: conv1 + tanh + 2x2 avgpool -> s_p1h (fp16) ----
    for (int idx=tid; idx<IMGS*84; idx+=THREADS) {
        const int img = idx/84, r2 = idx%84, c = r2/14, pw = r2%14;
        const uint* xim = s_xh + img*512 + pw;
        uint wp[5][3];
        #pragma unroll
        for (int k=0;k<15;k++) ((uint*)wp)[k] = s_whu[c*16 + k];
        const float bias = s_w[O_C1B + c];
        uint q[6][3], s[6][3];
        #pragma unroll
        for (int r=0;r<4;r++) ld_row(xim + r*16, q[r], s[r]);
        ushort* p1o = (ushort*)s_p1h + img*(P1_IMGU*2) + c*(P1_CHU*2) + pw;
        #pragma unroll
        for (int ph=0; ph<14; ph++) {
            ld_row(xim + (2*ph+4)*16, q[(2*ph+4)%6], s[(2*ph+4)%6]);
            ld_row(xim + (2*ph+5)*16, q[(2*ph+5)%6], s[(2*ph+5)%6]);
            float sum = 0.f;
            #pragma unroll
            for (int dy=0; dy<2; dy++)
            #pragma unroll
            for (int dx=0; dx<2; dx++) {
                float t = bias;
                #pragma unroll
                for (int ky=0; ky<5; ky++) {
                    const int sl = (2*ph+dy+ky)%6;
                    const uint* rr = dx ? s[sl] : q[sl];
                    t = fdot2(rr[0], wp[ky][0], t);
                    t = fdot2(rr[1], wp[ky][1], t);
                    t = fdot2(rr[2], wp[ky][2], t);
                }
                sum += fast_tanh(t);
            }
            p1o[ph*14] = f16rn(0.25f*sum);
        }
    }
    __syncthreads();

    // ---- stage 3: grouped C3 as MFMA GEMM: D[16 o][400 cols] = A[16][160] x B[160][400] ----
    // cols = (img, conv pixel) permuted so each 4-lane group is one 2x2 pool quad.
    {
        const int wv = tid >> 6;       // wave 0..3
        const int l  = tid & 63;
        const int lm = l & 15;         // A row m / B col n / C-D col
        const int lg = l >> 4;         // k-group (any consistent bijection works)
        // preload packed tap offsets: per K-step, 4 uints (8 taps)
        uint offr[5][4];
        #pragma unroll
        for (int kk=0; kk<5; kk++) {
            const uint* po = s_offs + kk*16 + lg*4;
            offr[kk][0]=po[0]; offr[kk][1]=po[1]; offr[kk][2]=po[2]; offr[kk][3]=po[3];
        }
        // preload A fragments: k = kk*32 + lg*8 + e, element addr = k*16 + m
        u32x4 afr[5];
        #pragma unroll
        for (int kk=0; kk<5; kk++) {
            const ushort* pa = s_At + (kk*32 + lg*8)*16 + lm;
            #pragma unroll
            for (int p=0; p<4; p++) {
                uint lo = pa[(2*p)*16], hi = pa[(2*p+1)*16];
                afr[kk][p] = pair16(hi, lo);
            }
        }
        const ushort* p1s = (const ushort*)s_p1h;
        for (int tile = wv; tile < 25; tile += 4) {
            const uint base = s_cb[tile*16 + lm];
            f32x4 d = {0.f, 0.f, 0.f, 0.f};
            #pragma unroll
            for (int kk=0; kk<5; kk++) {
                u32x4 b4;
                #pragma unroll
                for (int p=0; p<4; p++) {
                    const uint ow = offr[kk][p];
                    const uint lo = p1s[base + (ow & 0xffffu)];
                    const uint hi = p1s[base + (ow >> 16)];
                    b4[p] = pair16(hi, lo);
                }
                d = __builtin_amdgcn_mfma_f32_16x16x32_f16(
                        __builtin_bit_cast(h8, afr[kk]),
                        __builtin_bit_cast(h8, b4), d, 0, 0, 0);
            }
            // epilogue: bias + tanh, 2x2 pool within 4-lane quad, masked write
            const int obase = lg*4;
            const int Q = tile*4 + (lm >> 2);
            const uint qdest = s_qd[Q];
            #pragma unroll
            for (int rg=0; rg<4; rg++) {
                float v = fast_tanh(d[rg] + s_gb16[obase+rg]);
                v += __builtin_bit_cast(float, __builtin_amdgcn_ds_swizzle(__builtin_bit_cast(int, v), 0x041F));
                v += __builtin_bit_cast(float, __builtin_amdgcn_ds_swizzle(__builtin_bit_cast(int, v), 0x081F));
                if ((l & 3) == 0) {
                    ((ushort*)s_u)[qdest + (obase+rg)*25] = f16rn(0.25f*v);
                }
            }
        }
    }
    __syncthreads();

    // ---- stage 4: conv5 = 120x400 matvec + tanh -> c5 fp16 (b128 LDS reads) ----
    #pragma unroll
    for (int it=0; it<2; it++) {
        const int id2 = tid + THREADS*it;
        if (id2 < 120*IMGS) {
            const int f = id2 >> 2, img = id2 & 3;
            const uint4* pr4 = (const uint4*)(s_u + img * P2_IMGU);
            float a0=0.f, a1=0.f, a2=0.f, a3=0.f;
            if constexpr (H) {
                const uint4* wr = (const uint4*)(wsh + f*400);
                #pragma unroll 5
                for (int k=0;k<50;k++) {
                    uint4 w4 = wr[k];
                    uint4 p4 = pr4[k];
                    a0 = fdot2(p4.x, w4.x, a0);
                    a1 = fdot2(p4.y, w4.y, a1);
                    a2 = fdot2(p4.z, w4.z, a2);
                    a3 = fdot2(p4.w, w4.w, a3);
                }
            } else {
                const float4* wr = (const float4*)(c5_w + f*400);
                #pragma unroll 2
                for (int k=0;k<50;k++) {
                    float4 wa = wr[2*k], wb = wr[2*k+1];
                    uint4 p4 = pr4[k];
                    h2 h0 = __builtin_bit_cast(h2, p4.x);
                    h2 h1 = __builtin_bit_cast(h2, p4.y);
                    h2 hv = __builtin_bit_cast(h2, p4.z);
                    h2 h3 = __builtin_bit_cast(h2, p4.w);
                    a0 = fmaf((float)h0.x, wa.x, a0); a1 = fmaf((float)h0.y, wa.y, a1);
                    a2 = fmaf((float)h1.x, wa.z, a2); a3 = fmaf((float)h1.y, wa.w, a3);
                    a0 = fmaf((float)hv.x, wb.x, a0); a1 = fmaf((float)hv.y, wb.y, a1);
                    a2 = fmaf((float)h3.x, wb.z, a2); a3 = fmaf((float)h3.y, wb.w, a3);
                }
            }
            const uint bw = s_bh[f >> 1];
            const float bias = (f & 1) ? h2hi(bw) : h2lo(bw);
            ((ushort*)s_c5u)[img*(C5_IMGU*2) + f] =
                f16rn(fast_tanh((a0+a1)+(a2+a3) + bias));
        }
    }
    __syncthreads();

    // ---- stage 5: f6 (84x120) + tanh -> s_f6 fp32 (aliases dead p1) ----
    #pragma unroll
    for (int it=0; it<2; it++) {
        const int id2 = tid + THREADS*it;
        if (id2 < 84*IMGS) {
            const int j = id2 >> 2, img = id2 & 3;
            const uint4* cr4 = (const uint4*)(s_c5u + img * C5_IMGU);
            float a0=0.f, a1=0.f, a2=0.f, a3=0.f;
            if constexpr (H) {
                const uint4* wr = (const uint4*)(wsh + 48000 + j*120);
                #pragma unroll
                for (int k=0;k<15;k++) {
                    uint4 w4 = wr[k];
                    uint4 c4 = cr4[k];
                    a0 = fdot2(c4.x, w4.x, a0);
                    a1 = fdot2(c4.y, w4.y, a1);
                    a2 = fdot2(c4.z, w4.z, a2);
                    a3 = fdot2(c4.w, w4.w, a3);
                }
            } else {
                const float4* wr = (const float4*)(f6_w + j*120);
                #pragma unroll
                for (int k=0;k<15;k++) {
                    float4 wa = wr[2*k], wb = wr[2*k+1];
                    uint4 c4 = cr4[k];
                    h2 h0 = __builtin_bit_cast(h2, c4.x);
                    h2 h1 = __builtin_bit_cast(h2, c4.y);
                    h2 hv = __builtin_bit_cast(h2, c4.z);
                    h2 h3 = __builtin_bit_cast(h2, c4.w);
                    a0 = fmaf((float)h0.x, wa.x, a0); a1 = fmaf((float)h0.y, wa.y, a1);
                    a2 = fmaf((float)h1.x, wa.z, a2); a3 = fmaf((float)h1.y, wa.w, a3);
                    a0 = fmaf((float)hv.x, wb.x, a0); a1 = fmaf((float)hv.y, wb.y, a1);
                    a2 = fmaf((float)h3.x, wb.z, a2); a3 = fmaf((float)h3.y, wb.w, a3);
                }
            }
            const uint bw = s_bh[60 + (j >> 1)];
            const float bias = (j & 1) ? h2hi(bw) : h2lo(bw);
            s_f6[img*84 + j] = fast_tanh((a0+a1)+(a2+a3) + bias);
        }
    }
    __syncthreads();

    // ---- stage 6: out (10x84) -> global ----
    if (tid < 10*IMGS) {
        const int j = tid >> 2, img = tid & 3;
        const float* wr = out_w + j*84;
        const float* fr = s_f6 + img*84;
        float a0=0.f,a1=0.f,a2=0.f,a3=0.f;
        #pragma unroll
        for (int k=0;k<84;k+=4) {
            a0=fmaf(wr[k],  fr[k],  a0); a1=fmaf(wr[k+1],fr[k+1],a1);
            a2=fmaf(wr[k+2],fr[k+2],a2); a3=fmaf(wr[k+3],fr[k+3],a3);
        }
        out[((size_t)blk*IMGS + img)*10 + j] = (a0+a1)+(a2+a3) + out_b[j];
    }
}

extern "C" void kernel_launch(void* const* d_in, const int* in_sizes, int n_in,
                              void* d_out, int out_size, void* d_ws, size_t ws_size,
                              hipStream_t stream) {
    const float* x    = (const float*)d_in[0];
    const float* c1w  = (const float*)d_in[1];
    const float* c1b  = (const float*)d_in[2];
    const float* fsw  = (const float*)d_in[3];
    const float* fsb  = (const float*)d_in[4];
    const float* scw  = (const float*)d_in[5];
    const float* scb  = (const float*)d_in[6];
    const float* thw  = (const float*)d_in[7];
    const float* thb  = (const float*)d_in[8];
    const float* fow  = (const float*)d_in[9];
    const float* fob  = (const float*)d_in[10];
    const float* c5w  = (const float*)d_in[11];
    const float* c5b  = (const float*)d_in[12];
    const float* f6w  = (const float*)d_in[13];
    const float* f6b  = (const float*)d_in[14];
    const float* outw = (const float*)d_in[15];
    const float* outb = (const float*)d_in[16];
    float* outp = (float*)d_out;

    const int B = in_sizes[0] / 1024;     // 16384
    const int nblk = B / IMGS;            // 4096
    const size_t ws_need = (48000 + 10080) * sizeof(ushort);

    if (ws_size >= ws_need) {
        ushort* wsh = (ushort*)d_ws;
        cvt_w16<<<188, 256, 0, stream>>>(c5w, f6w, wsh);
        lenet_fused<true><<<nblk, THREADS, 0, stream>>>(
            x, c1w, c1b, fsw, fsb, scw, scb, thw, thb, fow, fob,
            c5w, c5b, f6w, f6b, outw, outb, wsh, outp);
    } else {
        lenet_fused<false><<<nblk, THREADS, 0, stream>>>(
            x, c1w, c1b, fsw, fsb, scw, scb, thw, thb, fow, fob,
            c5w, c5b, f6w, f6b, outw, outb, (const ushort*)nullptr, outp);
    }
}

// Round 15
// 177.985 us; speedup vs baseline: 1.4105x; 1.0397x over previous
//
#include <hip/hip_runtime.h>
#include <hip/hip_fp16.h>

#define THREADS 256
#define IMGS 4

// s_w (fp32): c1b[0..5], group biases [6..9]
#define O_C1B 0
#define O_GB  6

// p1 fp16 layout (uint units): ch stride mod32=9, img stride mod32=22
#define P1_CHU 105
#define P1_IMGU 630
// p2 fp16: 200 uints/img (400 halves), 16B-aligned
#define P2_IMGU 200
// c5 fp16: 60 uints/img (120 halves), 16B-aligned
#define C5_IMGU 60

// padded fp16 weight layouts in d_ws (halves):
//   c5: [128 rows][416 k]  (rows>=120 / k>=400 zero)   base 0
//   f6: [96 rows][128 k]   (rows>=84  / k>=120 zero)   base 53248
#define WS_C5K 416
#define WS_F6  53248
#define WS_F6K 128
#define WS_TOT 65536

typedef _Float16 h2 __attribute__((ext_vector_type(2)));
typedef _Float16 h8 __attribute__((ext_vector_type(8)));
typedef float    f32x4 __attribute__((ext_vector_type(4)));
typedef uint     u32x4 __attribute__((ext_vector_type(4)));

__device__ __forceinline__ float fdot2(uint a, uint b, float c) {
    return __builtin_amdgcn_fdot2(__builtin_bit_cast(h2, a), __builtin_bit_cast(h2, b), c, false);
}
__device__ __forceinline__ uint pkh2(float a, float b) {
    return __builtin_bit_cast(uint, __builtin_amdgcn_cvt_pkrtz(a, b));
}
__device__ __forceinline__ ushort f16rn(float a) {
    _Float16 h = (_Float16)a;
    return __builtin_bit_cast(ushort, h);
}
__device__ __forceinline__ float h2lo(uint w){ return (float)__builtin_bit_cast(h2, w).x; }
__device__ __forceinline__ float h2hi(uint w){ return (float)__builtin_bit_cast(h2, w).y; }

// combine two zero-extended u16 values into packed (lo, hi): one v_perm_b32
__device__ __forceinline__ uint pair16(uint hi, uint lo) {
    return __builtin_amdgcn_perm(hi, lo, 0x05040100u);
}
// (hi:lo) >> 16 -> one v_alignbit_b32
__device__ __forceinline__ uint funnel16(uint hi, uint lo) {
    return __builtin_amdgcn_alignbit(hi, lo, 16);
}

__device__ __forceinline__ float fast_tanh(float v) {
    float e = __expf(2.f * v);
    return 1.f - __fdividef(2.f, e + 1.f);
}

// load one 6-half row: q = aligned pairs, s = shifted-by-1 pairs
__device__ __forceinline__ void ld_row(const uint* p, uint* q, uint* s) {
    uint a = p[0], b = p[1], c = p[2];
    q[0] = a; q[1] = b; q[2] = c;
    s[0] = funnel16(b, a);
    s[1] = funnel16(c, b);
    s[2] = c >> 16;
}

// pre-kernel: convert c5_w / f6_w to zero-padded fp16 MFMA layouts in d_ws
__global__ __launch_bounds__(256)
void cvt_w16(const float* __restrict__ c5w, const float* __restrict__ f6w,
             ushort* __restrict__ ws) {
    int i = blockIdx.x * 256 + threadIdx.x;
    if (i < 53248) {
        int r = i / WS_C5K, k = i % WS_C5K;
        float v = (r < 120 && k < 400) ? c5w[r*400 + k] : 0.f;
        ws[i] = f16rn(v);
    }
    if (i < 12288) {
        int r = i / WS_F6K, k = i % WS_F6K;
        float v = (r < 84 && k < 120) ? f6w[r*120 + k] : 0.f;
        ws[WS_F6 + i] = f16rn(v);
    }
}

template<bool H>
__global__ __launch_bounds__(THREADS)
void lenet_fused(const float* __restrict__ x,
                 const float* __restrict__ c1_w, const float* __restrict__ c1_b,
                 const float* __restrict__ fs_w, const float* __restrict__ fs_b,
                 const float* __restrict__ sc_w, const float* __restrict__ sc_b,
                 const float* __restrict__ th_w, const float* __restrict__ th_b,
                 const float* __restrict__ fo_w, const float* __restrict__ fo_b,
                 const float* __restrict__ c5_w, const float* __restrict__ c5_b,
                 const float* __restrict__ f6_w, const float* __restrict__ f6_b,
                 const float* __restrict__ out_w, const float* __restrict__ out_b,
                 const ushort* __restrict__ wsh,
                 float* __restrict__ out)
{
    __shared__ uint   s_p1h[IMGS * P1_IMGU];  // 10080 B; f6 (fp32) aliases after stage 4
    __shared__ uint   s_whu[6 * 16];          // conv1 fp16 pair weights
    __shared__ float  s_w[10];                // fp32 biases
    __shared__ float  s_gb16[16];             // per-o group bias for stage 3
    __shared__ uint   s_bh[102];              // fp16 biases: c5b [0..59], f6b [60..101]
    __shared__ ushort s_At[160*16];           // A matrix [k][o] f16 (zero-padded grouping)
    __shared__ ushort s_cb[400];              // col -> p1 half-index base
    __shared__ uint   s_offs[80];             // packed tap offsets
    __shared__ ushort s_qd[100];              // quad -> p2 dest half-base
    __shared__ uint   s_u[IMGS * 512];        // 8192 B union: x fp16 / p2h+c5h
    uint*  s_xh  = s_u;
    uint*  s_c5u = s_u + IMGS * P2_IMGU;
    float* s_f6  = (float*)s_p1h;

    const int tid = threadIdx.x;
    const int blk = blockIdx.x;

    // ---- stage 0a: biases -> LDS ----
    if (tid < 6)  s_w[O_C1B + tid] = c1_b[tid];
    if (tid == 0){ s_w[O_GB+0]=fs_b[0]; s_w[O_GB+1]=sc_b[0]; s_w[O_GB+2]=th_b[0]; s_w[O_GB+3]=fo_b[0]; }
    if (tid < 16) s_gb16[tid] = tid<6 ? fs_b[0] : (tid<12 ? sc_b[0] : (tid<15 ? th_b[0] : fo_b[0]));
    if (tid < 60) s_bh[tid]      = pkh2(c5_b[2*tid], c5_b[2*tid+1]);
    if (tid < 42) s_bh[60 + tid] = pkh2(f6_b[2*tid], f6_b[2*tid+1]);

    // ---- stage 0b: conv1 weights -> packed fp16 pairs ----
    if (tid < 6) {
        const float* src = c1_w + tid*25;
        uint* dst = s_whu + tid*16;
        #pragma unroll
        for (int ky=0; ky<5; ky++) {
            dst[ky*3+0] = pkh2(src[ky*5+0], src[ky*5+1]);
            dst[ky*3+1] = pkh2(src[ky*5+2], src[ky*5+3]);
            dst[ky*3+2] = pkh2(src[ky*5+4], 0.f);
        }
    }

    // ---- stage 0c: MFMA tables (stage 3) ----
    for (int e = tid; e < 2560; e += THREADS) {
        const int t = e >> 4, o = e & 15;
        float v = 0.f;
        if (t < 150) {
            const int ch = t / 25, tap = t % 25;
            if (o < 6)       { int d = ch - o;      if (d < 0) d += 6; if (d < 3) v = fs_w[d*25 + tap]; }
            else if (o < 12) { int d = ch - (o-6);  if (d < 0) d += 6; if (d < 4) v = sc_w[d*25 + tap]; }
            else if (o < 15) { int d = ch - (o-12); if (d < 0) d += 6;
                               int j = (d<2) ? d : (d==3 ? 2 : (d==4 ? 3 : -1));
                               if (j >= 0) v = th_w[j*25 + tap]; }
            else             v = fo_w[ch*25 + tap];
        }
        s_At[t*16 + o] = f16rn(v);
    }
    for (int col = tid; col < 400; col += THREADS) {
        const int Q = col >> 2, corner = col & 3;
        const int img = Q / 25, q = Q % 25;
        const int qh = q / 5, qw = q % 5;
        const int h = 2*qh + (corner & 1);
        const int w = 2*qw + (corner >> 1);
        s_cb[col] = (ushort)(img*(P1_IMGU*2) + h*14 + w);
    }
    for (int i = tid; i < 80; i += THREADS) {
        uint o2[2];
        #pragma unroll
        for (int z=0; z<2; z++) {
            const int t = 2*i + z;
            if (t < 150) {
                const int ch = t/25, rem = t%25, ky = rem/5, kx = rem%5;
                o2[z] = (uint)(ch*(P1_CHU*2) + ky*14 + kx);
            } else o2[z] = 0u;
        }
        s_offs[i] = o2[0] | (o2[1] << 16);
    }
    for (int Q = tid; Q < 100; Q += THREADS) {
        s_qd[Q] = (ushort)((Q/25)*(P2_IMGU*2) + (Q%25));
    }

    // ---- stage 1: x -> LDS as fp16 pairs ----
    {
        const float4* xg = (const float4*)(x + (size_t)blk*(IMGS*1024));
        uint2* sx = (uint2*)s_u;
        #pragma unroll
        for (int i=0;i<(IMGS*1024/4)/THREADS;i++) {
            float4 v = xg[tid + i*THREADS];
            sx[tid + i*THREADS] = make_uint2(pkh2(v.x,v.y), pkh2(v.z,v.w));
        }
    }
    __syncthreads();

    // ---- stage 2: conv1 + tanh + 2x2 avgpool -> s_p1h (fp16) ----
    for (int idx=tid; idx<IMGS*84; idx+=THREADS) {
        const int img = idx/84, r2 = idx%84, c = r2/14, pw = r2%14;
        const uint* xim = s_xh + img*512 + pw;
        uint wp[5][3];
        #pragma unroll
        for (int k=0;k<15;k++) ((uint*)wp)[k] = s_whu[c*16 + k];
        const float bias = s_w[O_C1B + c];
        uint q[6][3], s[6][3];
        #pragma unroll
        for (int r=0;r<4;r++) ld_row(xim + r*16, q[r], s[r]);
        ushort* p1o = (ushort*)s_p1h + img*(P1_IMGU*2) + c*(P1_CHU*2) + pw;
        #pragma unroll
        for (int ph=0; ph<14; ph++) {
            ld_row(xim + (2*ph+4)*16, q[(2*ph+4)%6], s[(2*ph+4)%6]);
            ld_row(xim + (2*ph+5)*16, q[(2*ph+5)%6], s[(2*ph+5)%6]);
            float sum = 0.f;
            #pragma unroll
            for (int dy=0; dy<2; dy++)
            #pragma unroll
            for (int dx=0; dx<2; dx++) {
                float t = bias;
                #pragma unroll
                for (int ky=0; ky<5; ky++) {
                    const int sl = (2*ph+dy+ky)%6;
                    const uint* rr = dx ? s[sl] : q[sl];
                    t = fdot2(rr[0], wp[ky][0], t);
                    t = fdot2(rr[1], wp[ky][1], t);
                    t = fdot2(rr[2], wp[ky][2], t);
                }
                sum += fast_tanh(t);
            }
            p1o[ph*14] = f16rn(0.25f*sum);
        }
    }
    __syncthreads();

    // ---- stage 3: grouped C3 as MFMA GEMM ----
    {
        const int wv = tid >> 6;
        const int l  = tid & 63;
        const int lm = l & 15;
        const int lg = l >> 4;
        uint offr[5][4];
        #pragma unroll
        for (int kk=0; kk<5; kk++) {
            const uint* po = s_offs + kk*16 + lg*4;
            offr[kk][0]=po[0]; offr[kk][1]=po[1]; offr[kk][2]=po[2]; offr[kk][3]=po[3];
        }
        u32x4 afr[5];
        #pragma unroll
        for (int kk=0; kk<5; kk++) {
            const ushort* pa = s_At + (kk*32 + lg*8)*16 + lm;
            #pragma unroll
            for (int p=0; p<4; p++) {
                uint lo = pa[(2*p)*16], hi = pa[(2*p+1)*16];
                afr[kk][p] = pair16(hi, lo);
            }
        }
        const ushort* p1s = (const ushort*)s_p1h;
        for (int tile = wv; tile < 25; tile += 4) {
            const uint base = s_cb[tile*16 + lm];
            f32x4 d = {0.f, 0.f, 0.f, 0.f};
            #pragma unroll
            for (int kk=0; kk<5; kk++) {
                u32x4 b4;
                #pragma unroll
                for (int p=0; p<4; p++) {
                    const uint ow = offr[kk][p];
                    const uint lo = p1s[base + (ow & 0xffffu)];
                    const uint hi = p1s[base + (ow >> 16)];
                    b4[p] = pair16(hi, lo);
                }
                d = __builtin_amdgcn_mfma_f32_16x16x32_f16(
                        __builtin_bit_cast(h8, afr[kk]),
                        __builtin_bit_cast(h8, b4), d, 0, 0, 0);
            }
            const int obase = lg*4;
            const int Q = tile*4 + (lm >> 2);
            const uint qdest = s_qd[Q];
            #pragma unroll
            for (int rg=0; rg<4; rg++) {
                float v = fast_tanh(d[rg] + s_gb16[obase+rg]);
                v += __builtin_bit_cast(float, __builtin_amdgcn_ds_swizzle(__builtin_bit_cast(int, v), 0x041F));
                v += __builtin_bit_cast(float, __builtin_amdgcn_ds_swizzle(__builtin_bit_cast(int, v), 0x081F));
                if ((l & 3) == 0) {
                    ((ushort*)s_u)[qdest + (obase+rg)*25] = f16rn(0.25f*v);
                }
            }
        }
    }
    __syncthreads();

    // ---- stage 4: conv5 as MFMA GEMM: D[120 f][4 img] = W[120][400] x p2[400][4] ----
    if constexpr (H) {
        const int wv = tid >> 6;
        const int l  = tid & 63;
        const int lm = l & 15;
        const int lg = l >> 4;
        const ushort* p2s = (const ushort*)s_u + (lm & 3)*(P2_IMGU*2) + lg*8;
        #pragma unroll
        for (int tile = 0; tile < 2; tile++) {
            const int mt = wv + tile*4;    // M-tile 0..7
            const ushort* arow = wsh + (mt*16 + lm)*WS_C5K + lg*8;
            f32x4 d = {0.f, 0.f, 0.f, 0.f};
            #pragma unroll
            for (int ks=0; ks<13; ks++) {
                u32x4 a4 = *(const u32x4*)(arow + ks*32);
                u32x4 b4 = *(const u32x4*)(p2s + ks*32);
                d = __builtin_amdgcn_mfma_f32_16x16x32_f16(
                        __builtin_bit_cast(h8, a4),
                        __builtin_bit_cast(h8, b4), d, 0, 0, 0);
            }
            if (lm < 4) {
                #pragma unroll
                for (int rg=0; rg<4; rg++) {
                    const int f = mt*16 + lg*4 + rg;
                    if (f < 120) {
                        const uint bw = s_bh[f >> 1];
                        const float bias = (f & 1) ? h2hi(bw) : h2lo(bw);
                        ((ushort*)s_c5u)[lm*(C5_IMGU*2) + f] = f16rn(fast_tanh(d[rg] + bias));
                    }
                }
            }
        }
    } else {
        #pragma unroll
        for (int it=0; it<2; it++) {
            const int id2 = tid + THREADS*it;
            if (id2 < 120*IMGS) {
                const int f = id2 >> 2, img = id2 & 3;
                const uint4* pr4 = (const uint4*)(s_u + img * P2_IMGU);
                float a0=0.f, a1=0.f, a2=0.f, a3=0.f;
                const float4* wr = (const float4*)(c5_w + f*400);
                #pragma unroll 2
                for (int k=0;k<50;k++) {
                    float4 wa = wr[2*k], wb = wr[2*k+1];
                    uint4 p4 = pr4[k];
                    h2 h0 = __builtin_bit_cast(h2, p4.x);
                    h2 h1 = __builtin_bit_cast(h2, p4.y);
                    h2 hv = __builtin_bit_cast(h2, p4.z);
                    h2 h3 = __builtin_bit_cast(h2, p4.w);
                    a0 = fmaf((float)h0.x, wa.x, a0); a1 = fmaf((float)h0.y, wa.y, a1);
                    a2 = fmaf((float)h1.x, wa.z, a2); a3 = fmaf((float)h1.y, wa.w, a3);
                    a0 = fmaf((float)hv.x, wb.x, a0); a1 = fmaf((float)hv.y, wb.y, a1);
                    a2 = fmaf((float)h3.x, wb.z, a2); a3 = fmaf((float)h3.y, wb.w, a3);
                }
                const uint bw = s_bh[f >> 1];
                const float bias = (f & 1) ? h2hi(bw) : h2lo(bw);
                ((ushort*)s_c5u)[img*(C5_IMGU*2) + f] =
                    f16rn(fast_tanh((a0+a1)+(a2+a3) + bias));
            }
        }
    }
    __syncthreads();

    // ---- stage 5: f6 as MFMA GEMM: D[84 j][4 img] = W[84][120] x c5[120][4] ----
    if constexpr (H) {
        const int wv = tid >> 6;
        const int l  = tid & 63;
        const int lm = l & 15;
        const int lg = l >> 4;
        const ushort* c5s = (const ushort*)s_c5u + (lm & 3)*(C5_IMGU*2) + lg*8;
        for (int mt = wv; mt < 6; mt += 4) {
            const ushort* arow = wsh + WS_F6 + (mt*16 + lm)*WS_F6K + lg*8;
            f32x4 d = {0.f, 0.f, 0.f, 0.f};
            #pragma unroll
            for (int ks=0; ks<4; ks++) {
                u32x4 a4 = *(const u32x4*)(arow + ks*32);
                u32x4 b4 = *(const u32x4*)(c5s + ks*32);
                d = __builtin_amdgcn_mfma_f32_16x16x32_f16(
                        __builtin_bit_cast(h8, a4),
                        __builtin_bit_cast(h8, b4), d, 0, 0, 0);
            }
            if (lm < 4) {
                #pragma unroll
                for (int rg=0; rg<4; rg++) {
                    const int j = mt*16 + lg*4 + rg;
                    if (j < 84) {
                        const uint bw = s_bh[60 + (j >> 1)];
                        const float bias = (j & 1) ? h2hi(bw) : h2lo(bw);
                        s_f6[lm*84 + j] = fast_tanh(d[rg] + bias);
                    }
                }
            }
        }
    } else {
        #pragma unroll
        for (int it=0; it<2; it++) {
            const int id2 = tid + THREADS*it;
            if (id2 < 84*IMGS) {
                const int j = id2 >> 2, img = id2 & 3;
                const uint4* cr4 = (const uint4*)(s_c5u + img * C5_IMGU);
                float a0=0.f, a1=0.f, a2=0.f, a3=0.f;
                const float4* wr = (const float4*)(f6_w + j*120);
                #pragma unroll
                for (int k=0;k<15;k++) {
                    float4 wa = wr[2*k], wb = wr[2*k+1];
                    uint4 c4 = cr4[k];
                    h2 h0 = __builtin_bit_cast(h2, c4.x);
                    h2 h1 = __builtin_bit_cast(h2, c4.y);
                    h2 hv = __builtin_bit_cast(h2, c4.z);
                    h2 h3 = __builtin_bit_cast(h2, c4.w);
                    a0 = fmaf((float)h0.x, wa.x, a0); a1 = fmaf((float)h0.y, wa.y, a1);
                    a2 = fmaf((float)h1.x, wa.z, a2); a3 = fmaf((float)h1.y, wa.w, a3);
                    a0 = fmaf((float)hv.x, wb.x, a0); a1 = fmaf((float)hv.y, wb.y, a1);
                    a2 = fmaf((float)h3.x, wb.z, a2); a3 = fmaf((float)h3.y, wb.w, a3);
                }
                const uint bw = s_bh[60 + (j >> 1)];
                const float bias = (j & 1) ? h2hi(bw) : h2lo(bw);
                s_f6[img*84 + j] = fast_tanh((a0+a1)+(a2+a3) + bias);
            }
        }
    }
    __syncthreads();

    // ---- stage 6: out (10x84) -> global ----
    if (tid < 10*IMGS) {
        const int j = tid >> 2, img = tid & 3;
        const float* wr = out_w + j*84;
        const float* fr = s_f6 + img*84;
        float a0=0.f,a1=0.f,a2=0.f,a3=0.f;
        #pragma unroll
        for (int k=0;k<84;k+=4) {
            a0=fmaf(wr[k],  fr[k],  a0); a1=fmaf(wr[k+1],fr[k+1],a1);
            a2=fmaf(wr[k+2],fr[k+2],a2); a3=fmaf(wr[k+3],fr[k+3],a3);
        }
        out[((size_t)blk*IMGS + img)*10 + j] = (a0+a1)+(a2+a3) + out_b[j];
    }
}

extern "C" void kernel_launch(void* const* d_in, const int* in_sizes, int n_in,
                              void* d_out, int out_size, void* d_ws, size_t ws_size,
                              hipStream_t stream) {
    const float* x    = (const float*)d_in[0];
    const float* c1w  = (const float*)d_in[1];
    const float* c1b  = (const float*)d_in[2];
    const float* fsw  = (const float*)d_in[3];
    const float* fsb  = (const float*)d_in[4];
    const float* scw  = (const float*)d_in[5];
    const float* scb  = (const float*)d_in[6];
    const float* thw  = (const float*)d_in[7];
    const float* thb  = (const float*)d_in[8];
    const float* fow  = (const float*)d_in[9];
    const float* fob  = (const float*)d_in[10];
    const float* c5w  = (const float*)d_in[11];
    const float* c5b  = (const float*)d_in[12];
    const float* f6w  = (const float*)d_in[13];
    const float* f6b  = (const float*)d_in[14];
    const float* outw = (const float*)d_in[15];
    const float* outb = (const float*)d_in[16];
    float* outp = (float*)d_out;

    const int B = in_sizes[0] / 1024;     // 16384
    const int nblk = B / IMGS;            // 4096
    const size_t ws_need = (size_t)WS_TOT * sizeof(ushort);   // 131072 B

    if (ws_size >= ws_need) {
        ushort* wsh = (ushort*)d_ws;
        cvt_w16<<<208, 256, 0, stream>>>(c5w, f6w, wsh);
        lenet_fused<true><<<nblk, THREADS, 0, stream>>>(
            x, c1w, c1b, fsw, fsb, scw, scb, thw, thb, fow, fob,
            c5w, c5b, f6w, f6b, outw, outb, wsh, outp);
    } else {
        lenet_fused<false><<<nblk, THREADS, 0, stream>>>(
            x, c1w, c1b, fsw, fsb, scw, scb, thw, thb, fow, fob,
            c5w, c5b, f6w, f6b, outw, outb, (const ushort*)nullptr, outp);
    }
}

// Round 16
// 158.151 us; speedup vs baseline: 1.5874x; 1.1254x over previous
//
#include <hip/hip_runtime.h>
#include <hip/hip_fp16.h>

#define THREADS 256
#define IMGS 4

#define O_C1B 0
#define O_GB  6

// p1 fp16 layout (uint units): ch stride mod32=9, img stride mod32=22
#define P1_CHU 105
#define P1_IMGU 630
// p2 fp16: 200 uints/img (400 halves), 16B-aligned
#define P2_IMGU 200
// c5 fp16: 60 uints/img (120 halves), 16B-aligned
#define C5_IMGU 60

// d_ws layout (half-index):
//   c5 padded [128][416]              0      .. 53247
//   f6 padded [96][128]               53248  .. 65535
//   Atp packed A-frags (1280 uints)   65536  .. 68095
//   cb  (400 u16)                     68096  .. 68495
//   qd  (100 u16)                     68496  .. 68595
//   pad                               68596  .. 68607
//   offs (80 u32)                     68608  .. 68767
//   small blob (224 uints)            68768  .. 69215
#define WS_C5K   416
#define WS_F6    53248
#define WS_F6K   128
#define WS_ATP_H 65536
#define WS_CB    68096
#define WS_QD    68496
#define WS_OFFS_H 68608
#define WS_SB_H  68768
#define WS_NEED_BYTES 138432

typedef _Float16 h2 __attribute__((ext_vector_type(2)));
typedef _Float16 h8 __attribute__((ext_vector_type(8)));
typedef float    f32x4 __attribute__((ext_vector_type(4)));
typedef uint     u32x4 __attribute__((ext_vector_type(4)));

__device__ __forceinline__ float fdot2(uint a, uint b, float c) {
    return __builtin_amdgcn_fdot2(__builtin_bit_cast(h2, a), __builtin_bit_cast(h2, b), c, false);
}
__device__ __forceinline__ uint pkh2(float a, float b) {
    return __builtin_bit_cast(uint, __builtin_amdgcn_cvt_pkrtz(a, b));
}
__device__ __forceinline__ ushort f16rn(float a) {
    _Float16 h = (_Float16)a;
    return __builtin_bit_cast(ushort, h);
}
__device__ __forceinline__ float h2lo(uint w){ return (float)__builtin_bit_cast(h2, w).x; }
__device__ __forceinline__ float h2hi(uint w){ return (float)__builtin_bit_cast(h2, w).y; }

__device__ __forceinline__ uint pair16(uint hi, uint lo) {
    return __builtin_amdgcn_perm(hi, lo, 0x05040100u);
}
__device__ __forceinline__ uint funnel16(uint hi, uint lo) {
    return __builtin_amdgcn_alignbit(hi, lo, 16);
}

__device__ __forceinline__ float fast_tanh(float v) {
    float e = __expf(2.f * v);
    return 1.f - __fdividef(2.f, e + 1.f);
}

__device__ __forceinline__ void ld_row(const uint* p, uint* q, uint* s) {
    uint a = p[0], b = p[1], c = p[2];
    q[0] = a; q[1] = b; q[2] = c;
    s[0] = funnel16(b, a);
    s[1] = funnel16(c, b);
    s[2] = c >> 16;
}

// grouped-C3 A value: weight of output o at flat tap t (0..159), 0 if outside group
__device__ __forceinline__ float atval(int t, int o,
                                       const float* fsw, const float* scw,
                                       const float* thw, const float* fow) {
    float v = 0.f;
    if (t < 150) {
        const int ch = t / 25, tap = t % 25;
        if (o < 6)       { int d = ch - o;      if (d < 0) d += 6; if (d < 3) v = fsw[d*25 + tap]; }
        else if (o < 12) { int d = ch - (o-6);  if (d < 0) d += 6; if (d < 4) v = scw[d*25 + tap]; }
        else if (o < 15) { int d = ch - (o-12); if (d < 0) d += 6;
                           int j = (d<2) ? d : (d==3 ? 2 : (d==4 ? 3 : -1));
                           if (j >= 0) v = thw[j*25 + tap]; }
        else             v = fow[ch*25 + tap];
    }
    return v;
}

// pre-kernel: all input-independent tables -> d_ws
__global__ __launch_bounds__(256)
void cvt_tabs(const float* __restrict__ c1w, const float* __restrict__ c1b,
              const float* __restrict__ fsw, const float* __restrict__ fsb,
              const float* __restrict__ scw, const float* __restrict__ scb,
              const float* __restrict__ thw, const float* __restrict__ thb,
              const float* __restrict__ fow, const float* __restrict__ fob,
              const float* __restrict__ c5w, const float* __restrict__ c5b,
              const float* __restrict__ f6w, const float* __restrict__ f6b,
              ushort* __restrict__ ws) {
    const int i = blockIdx.x * 256 + threadIdx.x;
    if (i < 53248) {
        int r = i / WS_C5K, k = i % WS_C5K;
        float v = (r < 120 && k < 400) ? c5w[r*400 + k] : 0.f;
        ws[i] = f16rn(v);
    }
    if (i < 12288) {
        int r = i / WS_F6K, k = i % WS_F6K;
        float v = (r < 84 && k < 120) ? f6w[r*120 + k] : 0.f;
        ws[WS_F6 + i] = f16rn(v);
    }
    if (blockIdx.x == 0) {
        const int t = threadIdx.x;
        // Atp: packed per-lane A fragments [kk][lg][p][m] -> uint (2 halves)
        uint* wAtp = (uint*)(ws + WS_ATP_H);
        for (int idx = t; idx < 1280; idx += 256) {
            const int m = idx & 15, p = (idx >> 4) & 3, lg = (idx >> 6) & 3, kk = idx >> 8;
            const int tt = kk*32 + lg*8 + 2*p;
            wAtp[idx] = pkh2(atval(tt,   m, fsw, scw, thw, fow),
                             atval(tt+1, m, fsw, scw, thw, fow));
        }
        // cb: col -> p1 half-base
        for (int col = t; col < 400; col += 256) {
            const int Q = col >> 2, corner = col & 3;
            const int img = Q / 25, q = Q % 25;
            const int qh = q / 5, qw = q % 5;
            const int h = 2*qh + (corner & 1);
            const int w = 2*qw + (corner >> 1);
            ws[WS_CB + col] = (ushort)(img*(P1_IMGU*2) + h*14 + w);
        }
        // qd: quad -> p2 dest half-base
        for (int Q = t; Q < 100; Q += 256)
            ws[WS_QD + Q] = (ushort)((Q/25)*(P2_IMGU*2) + (Q%25));
        // offs: packed tap offsets
        uint* wo = (uint*)(ws + WS_OFFS_H);
        for (int i2 = t; i2 < 80; i2 += 256) {
            uint o2[2];
            #pragma unroll
            for (int z=0; z<2; z++) {
                const int tt = 2*i2 + z;
                if (tt < 150) {
                    const int ch = tt/25, rem = tt%25, ky = rem/5, kx = rem%5;
                    o2[z] = (uint)(ch*(P1_CHU*2) + ky*14 + kx);
                } else o2[z] = 0u;
            }
            wo[i2] = o2[0] | (o2[1] << 16);
        }
        // small blob: whu[0..95] | w[96..105] | gb16[106..121] | bh[122..223]
        uint* sb = (uint*)(ws + WS_SB_H);
        if (t < 6) {
            const float* src = c1w + t*25;
            uint* dst = sb + t*16;
            #pragma unroll
            for (int ky=0; ky<5; ky++) {
                dst[ky*3+0] = pkh2(src[ky*5+0], src[ky*5+1]);
                dst[ky*3+1] = pkh2(src[ky*5+2], src[ky*5+3]);
                dst[ky*3+2] = pkh2(src[ky*5+4], 0.f);
            }
            dst[15] = 0u;
        }
        float* wf = (float*)(sb + 96);
        if (t < 6) wf[O_C1B + t] = c1b[t];
        if (t == 0){ wf[O_GB+0]=fsb[0]; wf[O_GB+1]=scb[0]; wf[O_GB+2]=thb[0]; wf[O_GB+3]=fob[0]; }
        float* gbf = (float*)(sb + 106);
        if (t < 16) gbf[t] = t<6 ? fsb[0] : (t<12 ? scb[0] : (t<15 ? thb[0] : fob[0]));
        if (t < 60) sb[122 + t]      = pkh2(c5b[2*t], c5b[2*t+1]);
        if (t < 42) sb[122 + 60 + t] = pkh2(f6b[2*t], f6b[2*t+1]);
    }
}

// ============ main fused kernel (requires prepared ws) ============
__global__ __launch_bounds__(THREADS)
void lenet_ws(const float* __restrict__ x,
              const float* __restrict__ out_w, const float* __restrict__ out_b,
              const ushort* __restrict__ wsh,
              float* __restrict__ out)
{
    __shared__ uint s_p1h[IMGS * P1_IMGU];          // 10080 B; f6 fp32 aliases later
    __shared__ __align__(16) uint s_tbl[224];       // 896 B: whu | w | gb16 | bh
    __shared__ uint s_u[IMGS * 512];                // 8192 B: x fp16 / p2h+c5h
    uint*  s_whu  = s_tbl;
    float* s_w    = (float*)(s_tbl + 96);
    float* s_gb16 = (float*)(s_tbl + 106);
    uint*  s_bh   = s_tbl + 122;
    uint*  s_xh   = s_u;
    uint*  s_c5u  = s_u + IMGS * P2_IMGU;
    float* s_f6   = (float*)s_p1h;

    const int tid = threadIdx.x;
    const int blk = blockIdx.x;

    // ---- stage 0: copy small blob (56 x uint4) ----
    if (tid < 56) {
        ((uint4*)s_tbl)[tid] = ((const uint4*)(wsh + WS_SB_H))[tid];
    }

    // ---- stage 1: x -> LDS as fp16 pairs ----
    {
        const float4* xg = (const float4*)(x + (size_t)blk*(IMGS*1024));
        uint2* sx = (uint2*)s_u;
        #pragma unroll
        for (int i=0;i<(IMGS*1024/4)/THREADS;i++) {
            float4 v = xg[tid + i*THREADS];
            sx[tid + i*THREADS] = make_uint2(pkh2(v.x,v.y), pkh2(v.z,v.w));
        }
    }
    __syncthreads();

    // ---- stage 2: conv1 + tanh + 2x2 avgpool -> s_p1h (fp16) ----
    for (int idx=tid; idx<IMGS*84; idx+=THREADS) {
        const int img = idx/84, r2 = idx%84, c = r2/14, pw = r2%14;
        const uint* xim = s_xh + img*512 + pw;
        uint wp[5][3];
        #pragma unroll
        for (int k=0;k<15;k++) ((uint*)wp)[k] = s_whu[c*16 + k];
        const float bias = s_w[O_C1B + c];
        uint q[6][3], s[6][3];
        #pragma unroll
        for (int r=0;r<4;r++) ld_row(xim + r*16, q[r], s[r]);
        ushort* p1o = (ushort*)s_p1h + img*(P1_IMGU*2) + c*(P1_CHU*2) + pw;
        #pragma unroll
        for (int ph=0; ph<14; ph++) {
            ld_row(xim + (2*ph+4)*16, q[(2*ph+4)%6], s[(2*ph+4)%6]);
            ld_row(xim + (2*ph+5)*16, q[(2*ph+5)%6], s[(2*ph+5)%6]);
            float sum = 0.f;
            #pragma unroll
            for (int dy=0; dy<2; dy++)
            #pragma unroll
            for (int dx=0; dx<2; dx++) {
                float t = bias;
                #pragma unroll
                for (int ky=0; ky<5; ky++) {
                    const int sl = (2*ph+dy+ky)%6;
                    const uint* rr = dx ? s[sl] : q[sl];
                    t = fdot2(rr[0], wp[ky][0], t);
                    t = fdot2(rr[1], wp[ky][1], t);
                    t = fdot2(rr[2], wp[ky][2], t);
                }
                sum += fast_tanh(t);
            }
            p1o[ph*14] = f16rn(0.25f*sum);
        }
    }
    __syncthreads();

    // ---- stage 3: grouped C3 as MFMA GEMM (tables from global/L1) ----
    {
        const int wv = tid >> 6;
        const int l  = tid & 63;
        const int lm = l & 15;
        const int lg = l >> 4;
        const uint*   gAtp  = (const uint*)(wsh + WS_ATP_H);
        const uint*   goffs = (const uint*)(wsh + WS_OFFS_H);
        const ushort* gcb   = wsh + WS_CB;
        const ushort* gqd   = wsh + WS_QD;
        uint offr[5][4];
        #pragma unroll
        for (int kk=0; kk<5; kk++) {
            #pragma unroll
            for (int j=0; j<4; j++) offr[kk][j] = goffs[kk*16 + lg*4 + j];
        }
        u32x4 afr[5];
        #pragma unroll
        for (int kk=0; kk<5; kk++) {
            #pragma unroll
            for (int p=0; p<4; p++)
                afr[kk][p] = gAtp[((kk*4 + lg)*4 + p)*16 + lm];
        }
        const ushort* p1s = (const ushort*)s_p1h;
        for (int tile = wv; tile < 25; tile += 4) {
            const uint base = gcb[tile*16 + lm];
            f32x4 d = {0.f, 0.f, 0.f, 0.f};
            #pragma unroll
            for (int kk=0; kk<5; kk++) {
                u32x4 b4;
                #pragma unroll
                for (int p=0; p<4; p++) {
                    const uint ow = offr[kk][p];
                    const uint lo = p1s[base + (ow & 0xffffu)];
                    const uint hi = p1s[base + (ow >> 16)];
                    b4[p] = pair16(hi, lo);
                }
                d = __builtin_amdgcn_mfma_f32_16x16x32_f16(
                        __builtin_bit_cast(h8, afr[kk]),
                        __builtin_bit_cast(h8, b4), d, 0, 0, 0);
            }
            const int obase = lg*4;
            const int Q = tile*4 + (lm >> 2);
            const uint qdest = gqd[Q];
            #pragma unroll
            for (int rg=0; rg<4; rg++) {
                float v = fast_tanh(d[rg] + s_gb16[obase+rg]);
                v += __builtin_bit_cast(float, __builtin_amdgcn_ds_swizzle(__builtin_bit_cast(int, v), 0x041F));
                v += __builtin_bit_cast(float, __builtin_amdgcn_ds_swizzle(__builtin_bit_cast(int, v), 0x081F));
                if ((l & 3) == 0) {
                    ((ushort*)s_u)[qdest + (obase+rg)*25] = f16rn(0.25f*v);
                }
            }
        }
    }
    __syncthreads();

    // ---- stage 4: conv5 as MFMA GEMM ----
    {
        const int wv = tid >> 6;
        const int l  = tid & 63;
        const int lm = l & 15;
        const int lg = l >> 4;
        const ushort* p2s = (const ushort*)s_u + (lm & 3)*(P2_IMGU*2) + lg*8;
        #pragma unroll
        for (int tile = 0; tile < 2; tile++) {
            const int mt = wv + tile*4;
            const ushort* arow = wsh + (mt*16 + lm)*WS_C5K + lg*8;
            f32x4 d = {0.f, 0.f, 0.f, 0.f};
            #pragma unroll
            for (int ks=0; ks<13; ks++) {
                u32x4 a4 = *(const u32x4*)(arow + ks*32);
                u32x4 b4 = *(const u32x4*)(p2s + ks*32);
                d = __builtin_amdgcn_mfma_f32_16x16x32_f16(
                        __builtin_bit_cast(h8, a4),
                        __builtin_bit_cast(h8, b4), d, 0, 0, 0);
            }
            if (lm < 4) {
                #pragma unroll
                for (int rg=0; rg<4; rg++) {
                    const int f = mt*16 + lg*4 + rg;
                    if (f < 120) {
                        const uint bw = s_bh[f >> 1];
                        const float bias = (f & 1) ? h2hi(bw) : h2lo(bw);
                        ((ushort*)s_c5u)[lm*(C5_IMGU*2) + f] = f16rn(fast_tanh(d[rg] + bias));
                    }
                }
            }
        }
    }
    __syncthreads();

    // ---- stage 5: f6 as MFMA GEMM ----
    {
        const int wv = tid >> 6;
        const int l  = tid & 63;
        const int lm = l & 15;
        const int lg = l >> 4;
        const ushort* c5s = (const ushort*)s_c5u + (lm & 3)*(C5_IMGU*2) + lg*8;
        for (int mt = wv; mt < 6; mt += 4) {
            const ushort* arow = wsh + WS_F6 + (mt*16 + lm)*WS_F6K + lg*8;
            f32x4 d = {0.f, 0.f, 0.f, 0.f};
            #pragma unroll
            for (int ks=0; ks<4; ks++) {
                u32x4 a4 = *(const u32x4*)(arow + ks*32);
                u32x4 b4 = *(const u32x4*)(c5s + ks*32);
                d = __builtin_amdgcn_mfma_f32_16x16x32_f16(
                        __builtin_bit_cast(h8, a4),
                        __builtin_bit_cast(h8, b4), d, 0, 0, 0);
            }
            if (lm < 4) {
                #pragma unroll
                for (int rg=0; rg<4; rg++) {
                    const int j = mt*16 + lg*4 + rg;
                    if (j < 84) {
                        const uint bw = s_bh[60 + (j >> 1)];
                        const float bias = (j & 1) ? h2hi(bw) : h2lo(bw);
                        s_f6[lm*84 + j] = fast_tanh(d[rg] + bias);
                    }
                }
            }
        }
    }
    __syncthreads();

    // ---- stage 6: out (10x84) -> global ----
    if (tid < 10*IMGS) {
        const int j = tid >> 2, img = tid & 3;
        const float* wr = out_w + j*84;
        const float* fr = s_f6 + img*84;
        float a0=0.f,a1=0.f,a2=0.f,a3=0.f;
        #pragma unroll
        for (int k=0;k<84;k+=4) {
            a0=fmaf(wr[k],  fr[k],  a0); a1=fmaf(wr[k+1],fr[k+1],a1);
            a2=fmaf(wr[k+2],fr[k+2],a2); a3=fmaf(wr[k+3],fr[k+3],a3);
        }
        out[((size_t)blk*IMGS + img)*10 + j] = (a0+a1)+(a2+a3) + out_b[j];
    }
}

// ============ self-contained fallback (no ws needed) — R15 structure ============
__global__ __launch_bounds__(THREADS)
void lenet_nows(const float* __restrict__ x,
                const float* __restrict__ c1_w, const float* __restrict__ c1_b,
                const float* __restrict__ fs_w, const float* __restrict__ fs_b,
                const float* __restrict__ sc_w, const float* __restrict__ sc_b,
                const float* __restrict__ th_w, const float* __restrict__ th_b,
                const float* __restrict__ fo_w, const float* __restrict__ fo_b,
                const float* __restrict__ c5_w, const float* __restrict__ c5_b,
                const float* __restrict__ f6_w, const float* __restrict__ f6_b,
                const float* __restrict__ out_w, const float* __restrict__ out_b,
                float* __restrict__ out)
{
    __shared__ uint   s_p1h[IMGS * P1_IMGU];
    __shared__ uint   s_whu[6 * 16];
    __shared__ float  s_w[10];
    __shared__ float  s_gb16[16];
    __shared__ uint   s_bh[102];
    __shared__ ushort s_At[160*16];
    __shared__ ushort s_cb[400];
    __shared__ uint   s_offs[80];
    __shared__ ushort s_qd[100];
    __shared__ uint   s_u[IMGS * 512];
    uint*  s_xh  = s_u;
    uint*  s_c5u = s_u + IMGS * P2_IMGU;
    float* s_f6  = (float*)s_p1h;

    const int tid = threadIdx.x;
    const int blk = blockIdx.x;

    if (tid < 6)  s_w[O_C1B + tid] = c1_b[tid];
    if (tid == 0){ s_w[O_GB+0]=fs_b[0]; s_w[O_GB+1]=sc_b[0]; s_w[O_GB+2]=th_b[0]; s_w[O_GB+3]=fo_b[0]; }
    if (tid < 16) s_gb16[tid] = tid<6 ? fs_b[0] : (tid<12 ? sc_b[0] : (tid<15 ? th_b[0] : fo_b[0]));
    if (tid < 60) s_bh[tid]      = pkh2(c5_b[2*tid], c5_b[2*tid+1]);
    if (tid < 42) s_bh[60 + tid] = pkh2(f6_b[2*tid], f6_b[2*tid+1]);

    if (tid < 6) {
        const float* src = c1_w + tid*25;
        uint* dst = s_whu + tid*16;
        #pragma unroll
        for (int ky=0; ky<5; ky++) {
            dst[ky*3+0] = pkh2(src[ky*5+0], src[ky*5+1]);
            dst[ky*3+1] = pkh2(src[ky*5+2], src[ky*5+3]);
            dst[ky*3+2] = pkh2(src[ky*5+4], 0.f);
        }
    }

    for (int e = tid; e < 2560; e += THREADS) {
        const int t = e >> 4, o = e & 15;
        s_At[t*16 + o] = f16rn(atval(t, o, fs_w, sc_w, th_w, fo_w));
    }
    for (int col = tid; col < 400; col += THREADS) {
        const int Q = col >> 2, corner = col & 3;
        const int img = Q / 25, q = Q % 25;
        const int qh = q / 5, qw = q % 5;
        const int h = 2*qh + (corner & 1);
        const int w = 2*qw + (corner >> 1);
        s_cb[col] = (ushort)(img*(P1_IMGU*2) + h*14 + w);
    }
    for (int i = tid; i < 80; i += THREADS) {
        uint o2[2];
        #pragma unroll
        for (int z=0; z<2; z++) {
            const int t = 2*i + z;
            if (t < 150) {
                const int ch = t/25, rem = t%25, ky = rem/5, kx = rem%5;
                o2[z] = (uint)(ch*(P1_CHU*2) + ky*14 + kx);
            } else o2[z] = 0u;
        }
        s_offs[i] = o2[0] | (o2[1] << 16);
    }
    for (int Q = tid; Q < 100; Q += THREADS) {
        s_qd[Q] = (ushort)((Q/25)*(P2_IMGU*2) + (Q%25));
    }

    {
        const float4* xg = (const float4*)(x + (size_t)blk*(IMGS*1024));
        uint2* sx = (uint2*)s_u;
        #pragma unroll
        for (int i=0;i<(IMGS*1024/4)/THREADS;i++) {
            float4 v = xg[tid + i*THREADS];
            sx[tid + i*THREADS] = make_uint2(pkh2(v.x,v.y), pkh2(v.z,v.w));
        }
    }
    __syncthreads();

    for (int idx=tid; idx<IMGS*84; idx+=THREADS) {
        const int img = idx/84, r2 = idx%84, c = r2/14, pw = r2%14;
        const uint* xim = s_xh + img*512 + pw;
        uint wp[5][3];
        #pragma unroll
        for (int k=0;k<15;k++) ((uint*)wp)[k] = s_whu[c*16 + k];
        const float bias = s_w[O_C1B + c];
        uint q[6][3], s[6][3];
        #pragma unroll
        for (int r=0;r<4;r++) ld_row(xim + r*16, q[r], s[r]);
        ushort* p1o = (ushort*)s_p1h + img*(P1_IMGU*2) + c*(P1_CHU*2) + pw;
        #pragma unroll
        for (int ph=0; ph<14; ph++) {
            ld_row(xim + (2*ph+4)*16, q[(2*ph+4)%6], s[(2*ph+4)%6]);
            ld_row(xim + (2*ph+5)*16, q[(2*ph+5)%6], s[(2*ph+5)%6]);
            float sum = 0.f;
            #pragma unroll
            for (int dy=0; dy<2; dy++)
            #pragma unroll
            for (int dx=0; dx<2; dx++) {
                float t = bias;
                #pragma unroll
                for (int ky=0; ky<5; ky++) {
                    const int sl = (2*ph+dy+ky)%6;
                    const uint* rr = dx ? s[sl] : q[sl];
                    t = fdot2(rr[0], wp[ky][0], t);
                    t = fdot2(rr[1], wp[ky][1], t);
                    t = fdot2(rr[2], wp[ky][2], t);
                }
                sum += fast_tanh(t);
            }
            p1o[ph*14] = f16rn(0.25f*sum);
        }
    }
    __syncthreads();

    {
        const int wv = tid >> 6;
        const int l  = tid & 63;
        const int lm = l & 15;
        const int lg = l >> 4;
        uint offr[5][4];
        #pragma unroll
        for (int kk=0; kk<5; kk++) {
            const uint* po = s_offs + kk*16 + lg*4;
            offr[kk][0]=po[0]; offr[kk][1]=po[1]; offr[kk][2]=po[2]; offr[kk][3]=po[3];
        }
        u32x4 afr[5];
        #pragma unroll
        for (int kk=0; kk<5; kk++) {
            const ushort* pa = s_At + (kk*32 + lg*8)*16 + lm;
            #pragma unroll
            for (int p=0; p<4; p++) {
                uint lo = pa[(2*p)*16], hi = pa[(2*p+1)*16];
                afr[kk][p] = pair16(hi, lo);
            }
        }
        const ushort* p1s = (const ushort*)s_p1h;
        for (int tile = wv; tile < 25; tile += 4) {
            const uint base = s_cb[tile*16 + lm];
            f32x4 d = {0.f, 0.f, 0.f, 0.f};
            #pragma unroll
            for (int kk=0; kk<5; kk++) {
                u32x4 b4;
                #pragma unroll
                for (int p=0; p<4; p++) {
                    const uint ow = offr[kk][p];
                    const uint lo = p1s[base + (ow & 0xffffu)];
                    const uint hi = p1s[base + (ow >> 16)];
                    b4[p] = pair16(hi, lo);
                }
                d = __builtin_amdgcn_mfma_f32_16x16x32_f16(
                        __builtin_bit_cast(h8, afr[kk]),
                        __builtin_bit_cast(h8, b4), d, 0, 0, 0);
            }
            const int obase = lg*4;
            const int Q = tile*4 + (lm >> 2);
            const uint qdest = s_qd[Q];
            #pragma unroll
            for (int rg=0; rg<4; rg++) {
                float v = fast_tanh(d[rg] + s_gb16[obase+rg]);
                v += __builtin_bit_cast(float, __builtin_amdgcn_ds_swizzle(__builtin_bit_cast(int, v), 0x041F));
                v += __builtin_bit_cast(float, __builtin_amdgcn_ds_swizzle(__builtin_bit_cast(int, v), 0x081F));
                if ((l & 3) == 0) {
                    ((ushort*)s_u)[qdest + (obase+rg)*25] = f16rn(0.25f*v);
                }
            }
        }
    }
    __syncthreads();

    #pragma unroll
    for (int it=0; it<2; it++) {
        const int id2 = tid + THREADS*it;
        if (id2 < 120*IMGS) {
            const int f = id2 >> 2, img = id2 & 3;
            const uint4* pr4 = (const uint4*)(s_u + img * P2_IMGU);
            float a0=0.f, a1=0.f, a2=0.f, a3=0.f;
            const float4* wr = (const float4*)(c5_w + f*400);
            #pragma unroll 2
            for (int k=0;k<50;k++) {
                float4 wa = wr[2*k], wb = wr[2*k+1];
                uint4 p4 = pr4[k];
                h2 h0 = __builtin_bit_cast(h2, p4.x);
                h2 h1 = __builtin_bit_cast(h2, p4.y);
                h2 hv = __builtin_bit_cast(h2, p4.z);
                h2 h3 = __builtin_bit_cast(h2, p4.w);
                a0 = fmaf((float)h0.x, wa.x, a0); a1 = fmaf((float)h0.y, wa.y, a1);
                a2 = fmaf((float)h1.x, wa.z, a2); a3 = fmaf((float)h1.y, wa.w, a3);
                a0 = fmaf((float)hv.x, wb.x, a0); a1 = fmaf((float)hv.y, wb.y, a1);
                a2 = fmaf((float)h3.x, wb.z, a2); a3 = fmaf((float)h3.y, wb.w, a3);
            }
            const uint bw = s_bh[f >> 1];
            const float bias = (f & 1) ? h2hi(bw) : h2lo(bw);
            ((ushort*)s_c5u)[img*(C5_IMGU*2) + f] =
                f16rn(fast_tanh((a0+a1)+(a2+a3) + bias));
        }
    }
    __syncthreads();

    #pragma unroll
    for (int it=0; it<2; it++) {
        const int id2 = tid + THREADS*it;
        if (id2 < 84*IMGS) {
            const int j = id2 >> 2, img = id2 & 3;
            const uint4* cr4 = (const uint4*)(s_c5u + img * C5_IMGU);
            float a0=0.f, a1=0.f, a2=0.f, a3=0.f;
            const float4* wr = (const float4*)(f6_w + j*120);
            #pragma unroll
            for (int k=0;k<15;k++) {
                float4 wa = wr[2*k], wb = wr[2*k+1];
                uint4 c4 = cr4[k];
                h2 h0 = __builtin_bit_cast(h2, c4.x);
                h2 h1 = __builtin_bit_cast(h2, c4.y);
                h2 hv = __builtin_bit_cast(h2, c4.z);
                h2 h3 = __builtin_bit_cast(h2, c4.w);
                a0 = fmaf((float)h0.x, wa.x, a0); a1 = fmaf((float)h0.y, wa.y, a1);
                a2 = fmaf((float)h1.x, wa.z, a2); a3 = fmaf((float)h1.y, wa.w, a3);
                a0 = fmaf((float)hv.x, wb.x, a0); a1 = fmaf((float)hv.y, wb.y, a1);
                a2 = fmaf((float)h3.x, wb.z, a2); a3 = fmaf((float)h3.y, wb.w, a3);
            }
            const uint bw = s_bh[60 + (j >> 1)];
            const float bias = (j & 1) ? h2hi(bw) : h2lo(bw);
            s_f6[img*84 + j] = fast_tanh((a0+a1)+(a2+a3) + bias);
        }
    }
    __syncthreads();

    if (tid < 10*IMGS) {
        const int j = tid >> 2, img = tid & 3;
        const float* wr = out_w + j*84;
        const float* fr = s_f6 + img*84;
        float a0=0.f,a1=0.f,a2=0.f,a3=0.f;
        #pragma unroll
        for (int k=0;k<84;k+=4) {
            a0=fmaf(wr[k],  fr[k],  a0); a1=fmaf(wr[k+1],fr[k+1],a1);
            a2=fmaf(wr[k+2],fr[k+2],a2); a3=fmaf(wr[k+3],fr[k+3],a3);
        }
        out[((size_t)blk*IMGS + img)*10 + j] = (a0+a1)+(a2+a3) + out_b[j];
    }
}

extern "C" void kernel_launch(void* const* d_in, const int* in_sizes, int n_in,
                              void* d_out, int out_size, void* d_ws, size_t ws_size,
                              hipStream_t stream) {
    const float* x    = (const float*)d_in[0];
    const float* c1w  = (const float*)d_in[1];
    const float* c1b  = (const float*)d_in[2];
    const float* fsw  = (const float*)d_in[3];
    const float* fsb  = (const float*)d_in[4];
    const float* scw  = (const float*)d_in[5];
    const float* scb  = (const float*)d_in[6];
    const float* thw  = (const float*)d_in[7];
    const float* thb  = (const float*)d_in[8];
    const float* fow  = (const float*)d_in[9];
    const float* fob  = (const float*)d_in[10];
    const float* c5w  = (const float*)d_in[11];
    const float* c5b  = (const float*)d_in[12];
    const float* f6w  = (const float*)d_in[13];
    const float* f6b  = (const float*)d_in[14];
    const float* outw = (const float*)d_in[15];
    const float* outb = (const float*)d_in[16];
    float* outp = (float*)d_out;

    const int B = in_sizes[0] / 1024;     // 16384
    const int nblk = B / IMGS;            // 4096

    if (ws_size >= (size_t)WS_NEED_BYTES) {
        ushort* wsh = (ushort*)d_ws;
        cvt_tabs<<<208, 256, 0, stream>>>(c1w, c1b, fsw, fsb, scw, scb, thw, thb,
                                          fow, fob, c5w, c5b, f6w, f6b, wsh);
        lenet_ws<<<nblk, THREADS, 0, stream>>>(x, outw, outb, wsh, outp);
    } else {
        lenet_nows<<<nblk, THREADS, 0, stream>>>(
            x, c1w, c1b, fsw, fsb, scw, scb, thw, thb, fow, fob,
            c5w, c5b, f6w, f6b, outw, outb, outp);
    }
}

// Round 17
// 141.170 us; speedup vs baseline: 1.7783x; 1.1203x over previous
//
#include <hip/hip_runtime.h>
#include <hip/hip_fp16.h>

#define THREADS 512
#define IMGS 8

#define O_C1B 0
#define O_GB  6

// p1 fp16 layout (uint units): ch stride mod32=9, img stride mod32=22
#define P1_CHU 105
#define P1_IMGU 630
// p2 fp16: 200 uints/img (400 halves), 16B-aligned
#define P2_IMGU 200
// c5 fp16: 60 uints/img (120 halves), 16B-aligned
#define C5_IMGU 60

// d_ws layout (half-index):
#define WS_C5K   416
#define WS_F6    53248
#define WS_F6K   128
#define WS_ATP_H 65536
#define WS_CB    68096
#define WS_QD    68896
#define WS_OFFS_H 69096
#define WS_SB_H  69256
#define WS_NEED_BYTES 139408

typedef _Float16 h2 __attribute__((ext_vector_type(2)));
typedef _Float16 h8 __attribute__((ext_vector_type(8)));
typedef float    f32x4 __attribute__((ext_vector_type(4)));
typedef uint     u32x4 __attribute__((ext_vector_type(4)));

__device__ __forceinline__ float fdot2(uint a, uint b, float c) {
    return __builtin_amdgcn_fdot2(__builtin_bit_cast(h2, a), __builtin_bit_cast(h2, b), c, false);
}
__device__ __forceinline__ uint pkh2(float a, float b) {
    return __builtin_bit_cast(uint, __builtin_amdgcn_cvt_pkrtz(a, b));
}
__device__ __forceinline__ ushort f16rn(float a) {
    _Float16 h = (_Float16)a;
    return __builtin_bit_cast(ushort, h);
}
__device__ __forceinline__ float h2lo(uint w){ return (float)__builtin_bit_cast(h2, w).x; }
__device__ __forceinline__ float h2hi(uint w){ return (float)__builtin_bit_cast(h2, w).y; }

__device__ __forceinline__ uint pair16(uint hi, uint lo) {
    return __builtin_amdgcn_perm(hi, lo, 0x05040100u);
}
__device__ __forceinline__ uint funnel16(uint hi, uint lo) {
    return __builtin_amdgcn_alignbit(hi, lo, 16);
}

__device__ __forceinline__ float fast_tanh(float v) {
    float e = __expf(2.f * v);
    return 1.f - __fdividef(2.f, e + 1.f);
}

__device__ __forceinline__ void ld_row(const uint* p, uint* q, uint* s) {
    uint a = p[0], b = p[1], c = p[2];
    q[0] = a; q[1] = b; q[2] = c;
    s[0] = funnel16(b, a);
    s[1] = funnel16(c, b);
    s[2] = c >> 16;
}

// grouped-C3 A value: weight of output o at flat tap t (0..159), 0 if outside group
__device__ __forceinline__ float atval(int t, int o,
                                       const float* fsw, const float* scw,
                                       const float* thw, const float* fow) {
    float v = 0.f;
    if (t < 150) {
        const int ch = t / 25, tap = t % 25;
        if (o < 6)       { int d = ch - o;      if (d < 0) d += 6; if (d < 3) v = fsw[d*25 + tap]; }
        else if (o < 12) { int d = ch - (o-6);  if (d < 0) d += 6; if (d < 4) v = scw[d*25 + tap]; }
        else if (o < 15) { int d = ch - (o-12); if (d < 0) d += 6;
                           int j = (d<2) ? d : (d==3 ? 2 : (d==4 ? 3 : -1));
                           if (j >= 0) v = thw[j*25 + tap]; }
        else             v = fow[ch*25 + tap];
    }
    return v;
}

// pre-kernel: all input-independent tables -> d_ws
__global__ __launch_bounds__(256)
void cvt_tabs(const float* __restrict__ c1w, const float* __restrict__ c1b,
              const float* __restrict__ fsw, const float* __restrict__ fsb,
              const float* __restrict__ scw, const float* __restrict__ scb,
              const float* __restrict__ thw, const float* __restrict__ thb,
              const float* __restrict__ fow, const float* __restrict__ fob,
              const float* __restrict__ c5w, const float* __restrict__ c5b,
              const float* __restrict__ f6w, const float* __restrict__ f6b,
              ushort* __restrict__ ws) {
    const int i = blockIdx.x * 256 + threadIdx.x;
    if (i < 53248) {
        int r = i / WS_C5K, k = i % WS_C5K;
        float v = (r < 120 && k < 400) ? c5w[r*400 + k] : 0.f;
        ws[i] = f16rn(v);
    }
    if (i < 12288) {
        int r = i / WS_F6K, k = i % WS_F6K;
        float v = (r < 84 && k < 120) ? f6w[r*120 + k] : 0.f;
        ws[WS_F6 + i] = f16rn(v);
    }
    if (blockIdx.x == 0) {
        const int t = threadIdx.x;
        uint* wAtp = (uint*)(ws + WS_ATP_H);
        for (int idx = t; idx < 1280; idx += 256) {
            const int m = idx & 15, p = (idx >> 4) & 3, lg = (idx >> 6) & 3, kk = idx >> 8;
            const int tt = kk*32 + lg*8 + 2*p;
            wAtp[idx] = pkh2(atval(tt,   m, fsw, scw, thw, fow),
                             atval(tt+1, m, fsw, scw, thw, fow));
        }
        // cb: col -> p1 half-base (800 cols: 8 imgs x 25 quads x 4 corners)
        for (int col = t; col < 800; col += 256) {
            const int Q = col >> 2, corner = col & 3;
            const int img = Q / 25, q = Q % 25;
            const int qh = q / 5, qw = q % 5;
            const int h = 2*qh + (corner & 1);
            const int w = 2*qw + (corner >> 1);
            ws[WS_CB + col] = (ushort)(img*(P1_IMGU*2) + h*14 + w);
        }
        // qd: quad -> p2 dest half-base (200 quads)
        for (int Q = t; Q < 200; Q += 256)
            ws[WS_QD + Q] = (ushort)((Q/25)*(P2_IMGU*2) + (Q%25));
        // offs: packed tap offsets
        uint* wo = (uint*)(ws + WS_OFFS_H);
        for (int i2 = t; i2 < 80; i2 += 256) {
            uint o2[2];
            #pragma unroll
            for (int z=0; z<2; z++) {
                const int tt = 2*i2 + z;
                if (tt < 150) {
                    const int ch = tt/25, rem = tt%25, ky = rem/5, kx = rem%5;
                    o2[z] = (uint)(ch*(P1_CHU*2) + ky*14 + kx);
                } else o2[z] = 0u;
            }
            wo[i2] = o2[0] | (o2[1] << 16);
        }
        // small blob: whu[0..95] | w[96..105] | gb16[106..121] | bh[122..223]
        uint* sb = (uint*)(ws + WS_SB_H);
        if (t < 6) {
            const float* src = c1w + t*25;
            uint* dst = sb + t*16;
            #pragma unroll
            for (int ky=0; ky<5; ky++) {
                dst[ky*3+0] = pkh2(src[ky*5+0], src[ky*5+1]);
                dst[ky*3+1] = pkh2(src[ky*5+2], src[ky*5+3]);
                dst[ky*3+2] = pkh2(src[ky*5+4], 0.f);
            }
            dst[15] = 0u;
        }
        float* wf = (float*)(sb + 96);
        if (t < 6) wf[O_C1B + t] = c1b[t];
        if (t == 0){ wf[O_GB+0]=fsb[0]; wf[O_GB+1]=scb[0]; wf[O_GB+2]=thb[0]; wf[O_GB+3]=fob[0]; }
        float* gbf = (float*)(sb + 106);
        if (t < 16) gbf[t] = t<6 ? fsb[0] : (t<12 ? scb[0] : (t<15 ? thb[0] : fob[0]));
        if (t < 60) sb[122 + t]      = pkh2(c5b[2*t], c5b[2*t+1]);
        if (t < 42) sb[122 + 60 + t] = pkh2(f6b[2*t], f6b[2*t+1]);
    }
}

// ============ main fused kernel (requires prepared ws) — IMGS=8, 512 thr ============
__global__ __launch_bounds__(THREADS)
void lenet_ws(const float* __restrict__ x,
              const float* __restrict__ out_w, const float* __restrict__ out_b,
              const ushort* __restrict__ wsh,
              float* __restrict__ out)
{
    __shared__ uint s_p1h[IMGS * P1_IMGU];          // 20160 B; f6 fp32 aliases later
    __shared__ __align__(16) uint s_tbl[224];       // 896 B: whu | w | gb16 | bh
    __shared__ uint s_u[IMGS * 512];                // 16384 B: x fp16 / p2h+c5h
    uint*  s_whu  = s_tbl;
    float* s_w    = (float*)(s_tbl + 96);
    float* s_gb16 = (float*)(s_tbl + 106);
    uint*  s_bh   = s_tbl + 122;
    uint*  s_xh   = s_u;
    uint*  s_c5u  = s_u + IMGS * P2_IMGU;           // uints 1600..2079
    float* s_f6   = (float*)s_p1h;

    const int tid = threadIdx.x;
    const int blk = blockIdx.x;

    // ---- stage 0: copy small blob (56 x uint4) ----
    if (tid < 56) {
        ((uint4*)s_tbl)[tid] = ((const uint4*)(wsh + WS_SB_H))[tid];
    }

    // ---- stage 1: x -> LDS as fp16 pairs ----
    {
        const float4* xg = (const float4*)(x + (size_t)blk*(IMGS*1024));
        uint2* sx = (uint2*)s_u;
        #pragma unroll
        for (int i=0;i<(IMGS*1024/4)/THREADS;i++) {
            float4 v = xg[tid + i*THREADS];
            sx[tid + i*THREADS] = make_uint2(pkh2(v.x,v.y), pkh2(v.z,v.w));
        }
    }
    __syncthreads();

    // ---- stage 2: conv1 + tanh + 2x2 avgpool -> s_p1h (fp16) ----
    for (int idx=tid; idx<IMGS*84; idx+=THREADS) {
        const int img = idx/84, r2 = idx%84, c = r2/14, pw = r2%14;
        const uint* xim = s_xh + img*512 + pw;
        uint wp[5][3];
        #pragma unroll
        for (int k=0;k<15;k++) ((uint*)wp)[k] = s_whu[c*16 + k];
        const float bias = s_w[O_C1B + c];
        uint q[6][3], s[6][3];
        #pragma unroll
        for (int r=0;r<4;r++) ld_row(xim + r*16, q[r], s[r]);
        ushort* p1o = (ushort*)s_p1h + img*(P1_IMGU*2) + c*(P1_CHU*2) + pw;
        #pragma unroll
        for (int ph=0; ph<14; ph++) {
            ld_row(xim + (2*ph+4)*16, q[(2*ph+4)%6], s[(2*ph+4)%6]);
            ld_row(xim + (2*ph+5)*16, q[(2*ph+5)%6], s[(2*ph+5)%6]);
            float sum = 0.f;
            #pragma unroll
            for (int dy=0; dy<2; dy++)
            #pragma unroll
            for (int dx=0; dx<2; dx++) {
                float t = bias;
                #pragma unroll
                for (int ky=0; ky<5; ky++) {
                    const int sl = (2*ph+dy+ky)%6;
                    const uint* rr = dx ? s[sl] : q[sl];
                    t = fdot2(rr[0], wp[ky][0], t);
                    t = fdot2(rr[1], wp[ky][1], t);
                    t = fdot2(rr[2], wp[ky][2], t);
                }
                sum += fast_tanh(t);
            }
            p1o[ph*14] = f16rn(0.25f*sum);
        }
    }
    __syncthreads();

    // ---- stage 3: grouped C3 as MFMA GEMM (50 N-tiles over 8 waves) ----
    {
        const int wv = tid >> 6;
        const int l  = tid & 63;
        const int lm = l & 15;
        const int lg = l >> 4;
        const uint*   gAtp  = (const uint*)(wsh + WS_ATP_H);
        const uint*   goffs = (const uint*)(wsh + WS_OFFS_H);
        const ushort* gcb   = wsh + WS_CB;
        const ushort* gqd   = wsh + WS_QD;
        uint offr[5][4];
        #pragma unroll
        for (int kk=0; kk<5; kk++) {
            #pragma unroll
            for (int j=0; j<4; j++) offr[kk][j] = goffs[kk*16 + lg*4 + j];
        }
        u32x4 afr[5];
        #pragma unroll
        for (int kk=0; kk<5; kk++) {
            #pragma unroll
            for (int p=0; p<4; p++)
                afr[kk][p] = gAtp[((kk*4 + lg)*4 + p)*16 + lm];
        }
        const ushort* p1s = (const ushort*)s_p1h;
        for (int tile = wv; tile < 50; tile += 8) {
            const uint base = gcb[tile*16 + lm];
            f32x4 d = {0.f, 0.f, 0.f, 0.f};
            #pragma unroll
            for (int kk=0; kk<5; kk++) {
                u32x4 b4;
                #pragma unroll
                for (int p=0; p<4; p++) {
                    const uint ow = offr[kk][p];
                    const uint lo = p1s[base + (ow & 0xffffu)];
                    const uint hi = p1s[base + (ow >> 16)];
                    b4[p] = pair16(hi, lo);
                }
                d = __builtin_amdgcn_mfma_f32_16x16x32_f16(
                        __builtin_bit_cast(h8, afr[kk]),
                        __builtin_bit_cast(h8, b4), d, 0, 0, 0);
            }
            const int obase = lg*4;
            const int Q = tile*4 + (lm >> 2);
            const uint qdest = gqd[Q];
            #pragma unroll
            for (int rg=0; rg<4; rg++) {
                float v = fast_tanh(d[rg] + s_gb16[obase+rg]);
                v += __builtin_bit_cast(float, __builtin_amdgcn_ds_swizzle(__builtin_bit_cast(int, v), 0x041F));
                v += __builtin_bit_cast(float, __builtin_amdgcn_ds_swizzle(__builtin_bit_cast(int, v), 0x081F));
                if ((l & 3) == 0) {
                    ((ushort*)s_u)[qdest + (obase+rg)*25] = f16rn(0.25f*v);
                }
            }
        }
    }
    __syncthreads();

    // ---- stage 4: conv5 as MFMA GEMM: D[120 f][8 img] — 8 M-tiles over 8 waves ----
    {
        const int wv = tid >> 6;
        const int l  = tid & 63;
        const int lm = l & 15;
        const int lg = l >> 4;
        const ushort* p2s = (const ushort*)s_u + (lm & 7)*(P2_IMGU*2) + lg*8;
        const int mt = wv;                     // M-tile 0..7
        const ushort* arow = wsh + (mt*16 + lm)*WS_C5K + lg*8;
        f32x4 d = {0.f, 0.f, 0.f, 0.f};
        #pragma unroll
        for (int ks=0; ks<13; ks++) {
            u32x4 a4 = *(const u32x4*)(arow + ks*32);
            u32x4 b4 = *(const u32x4*)(p2s + ks*32);
            d = __builtin_amdgcn_mfma_f32_16x16x32_f16(
                    __builtin_bit_cast(h8, a4),
                    __builtin_bit_cast(h8, b4), d, 0, 0, 0);
        }
        if (lm < 8) {
            #pragma unroll
            for (int rg=0; rg<4; rg++) {
                const int f = mt*16 + lg*4 + rg;
                if (f < 120) {
                    const uint bw = s_bh[f >> 1];
                    const float bias = (f & 1) ? h2hi(bw) : h2lo(bw);
                    ((ushort*)s_c5u)[lm*(C5_IMGU*2) + f] = f16rn(fast_tanh(d[rg] + bias));
                }
            }
        }
    }
    __syncthreads();

    // ---- stage 5: f6 as MFMA GEMM: D[84 j][8 img] — 6 M-tiles, waves 0-5 ----
    {
        const int wv = tid >> 6;
        const int l  = tid & 63;
        const int lm = l & 15;
        const int lg = l >> 4;
        if (wv < 6) {
            const ushort* c5s = (const ushort*)s_c5u + (lm & 7)*(C5_IMGU*2) + lg*8;
            const int mt = wv;
            const ushort* arow = wsh + WS_F6 + (mt*16 + lm)*WS_F6K + lg*8;
            f32x4 d = {0.f, 0.f, 0.f, 0.f};
            #pragma unroll
            for (int ks=0; ks<4; ks++) {
                u32x4 a4 = *(const u32x4*)(arow + ks*32);
                u32x4 b4 = *(const u32x4*)(c5s + ks*32);
                d = __builtin_amdgcn_mfma_f32_16x16x32_f16(
                        __builtin_bit_cast(h8, a4),
                        __builtin_bit_cast(h8, b4), d, 0, 0, 0);
            }
            if (lm < 8) {
                #pragma unroll
                for (int rg=0; rg<4; rg++) {
                    const int j = mt*16 + lg*4 + rg;
                    if (j < 84) {
                        const uint bw = s_bh[60 + (j >> 1)];
                        const float bias = (j & 1) ? h2hi(bw) : h2lo(bw);
                        s_f6[lm*84 + j] = fast_tanh(d[rg] + bias);
                    }
                }
            }
        }
    }
    __syncthreads();

    // ---- stage 6: out (10x84) -> global ----
    if (tid < 10*IMGS) {
        const int j = tid >> 3, img = tid & 7;
        const float* wr = out_w + j*84;
        const float* fr = s_f6 + img*84;
        float a0=0.f,a1=0.f,a2=0.f,a3=0.f;
        #pragma unroll
        for (int k=0;k<84;k+=4) {
            a0=fmaf(wr[k],  fr[k],  a0); a1=fmaf(wr[k+1],fr[k+1],a1);
            a2=fmaf(wr[k+2],fr[k+2],a2); a3=fmaf(wr[k+3],fr[k+3],a3);
        }
        out[((size_t)blk*IMGS + img)*10 + j] = (a0+a1)+(a2+a3) + out_b[j];
    }
}

// ============ self-contained fallback (no ws) — R15 structure, IMGS=4 ============
#define FB_IMGS 4
#define FB_THREADS 256
__global__ __launch_bounds__(FB_THREADS)
void lenet_nows(const float* __restrict__ x,
                const float* __restrict__ c1_w, const float* __restrict__ c1_b,
                const float* __restrict__ fs_w, const float* __restrict__ fs_b,
                const float* __restrict__ sc_w, const float* __restrict__ sc_b,
                const float* __restrict__ th_w, const float* __restrict__ th_b,
                const float* __restrict__ fo_w, const float* __restrict__ fo_b,
                const float* __restrict__ c5_w, const float* __restrict__ c5_b,
                const float* __restrict__ f6_w, const float* __restrict__ f6_b,
                const float* __restrict__ out_w, const float* __restrict__ out_b,
                float* __restrict__ out)
{
    __shared__ uint   s_p1h[FB_IMGS * P1_IMGU];
    __shared__ uint   s_whu[6 * 16];
    __shared__ float  s_w[10];
    __shared__ float  s_gb16[16];
    __shared__ uint   s_bh[102];
    __shared__ ushort s_At[160*16];
    __shared__ ushort s_cb[400];
    __shared__ uint   s_offs[80];
    __shared__ ushort s_qd[100];
    __shared__ uint   s_u[FB_IMGS * 512];
    uint*  s_xh  = s_u;
    uint*  s_c5u = s_u + FB_IMGS * P2_IMGU;
    float* s_f6  = (float*)s_p1h;

    const int tid = threadIdx.x;
    const int blk = blockIdx.x;

    if (tid < 6)  s_w[O_C1B + tid] = c1_b[tid];
    if (tid == 0){ s_w[O_GB+0]=fs_b[0]; s_w[O_GB+1]=sc_b[0]; s_w[O_GB+2]=th_b[0]; s_w[O_GB+3]=fo_b[0]; }
    if (tid < 16) s_gb16[tid] = tid<6 ? fs_b[0] : (tid<12 ? sc_b[0] : (tid<15 ? th_b[0] : fo_b[0]));
    if (tid < 60) s_bh[tid]      = pkh2(c5_b[2*tid], c5_b[2*tid+1]);
    if (tid < 42) s_bh[60 + tid] = pkh2(f6_b[2*tid], f6_b[2*tid+1]);

    if (tid < 6) {
        const float* src = c1_w + tid*25;
        uint* dst = s_whu + tid*16;
        #pragma unroll
        for (int ky=0; ky<5; ky++) {
            dst[ky*3+0] = pkh2(src[ky*5+0], src[ky*5+1]);
            dst[ky*3+1] = pkh2(src[ky*5+2], src[ky*5+3]);
            dst[ky*3+2] = pkh2(src[ky*5+4], 0.f);
        }
    }

    for (int e = tid; e < 2560; e += FB_THREADS) {
        const int t = e >> 4, o = e & 15;
        s_At[t*16 + o] = f16rn(atval(t, o, fs_w, sc_w, th_w, fo_w));
    }
    for (int col = tid; col < 400; col += FB_THREADS) {
        const int Q = col >> 2, corner = col & 3;
        const int img = Q / 25, q = Q % 25;
        const int qh = q / 5, qw = q % 5;
        const int h = 2*qh + (corner & 1);
        const int w = 2*qw + (corner >> 1);
        s_cb[col] = (ushort)(img*(P1_IMGU*2) + h*14 + w);
    }
    for (int i = tid; i < 80; i += FB_THREADS) {
        uint o2[2];
        #pragma unroll
        for (int z=0; z<2; z++) {
            const int t = 2*i + z;
            if (t < 150) {
                const int ch = t/25, rem = t%25, ky = rem/5, kx = rem%5;
                o2[z] = (uint)(ch*(P1_CHU*2) + ky*14 + kx);
            } else o2[z] = 0u;
        }
        s_offs[i] = o2[0] | (o2[1] << 16);
    }
    for (int Q = tid; Q < 100; Q += FB_THREADS) {
        s_qd[Q] = (ushort)((Q/25)*(P2_IMGU*2) + (Q%25));
    }

    {
        const float4* xg = (const float4*)(x + (size_t)blk*(FB_IMGS*1024));
        uint2* sx = (uint2*)s_u;
        #pragma unroll
        for (int i=0;i<(FB_IMGS*1024/4)/FB_THREADS;i++) {
            float4 v = xg[tid + i*FB_THREADS];
            sx[tid + i*FB_THREADS] = make_uint2(pkh2(v.x,v.y), pkh2(v.z,v.w));
        }
    }
    __syncthreads();

    for (int idx=tid; idx<FB_IMGS*84; idx+=FB_THREADS) {
        const int img = idx/84, r2 = idx%84, c = r2/14, pw = r2%14;
        const uint* xim = s_xh + img*512 + pw;
        uint wp[5][3];
        #pragma unroll
        for (int k=0;k<15;k++) ((uint*)wp)[k] = s_whu[c*16 + k];
        const float bias = s_w[O_C1B + c];
        uint q[6][3], s[6][3];
        #pragma unroll
        for (int r=0;r<4;r++) ld_row(xim + r*16, q[r], s[r]);
        ushort* p1o = (ushort*)s_p1h + img*(P1_IMGU*2) + c*(P1_CHU*2) + pw;
        #pragma unroll
        for (int ph=0; ph<14; ph++) {
            ld_row(xim + (2*ph+4)*16, q[(2*ph+4)%6], s[(2*ph+4)%6]);
            ld_row(xim + (2*ph+5)*16, q[(2*ph+5)%6], s[(2*ph+5)%6]);
            float sum = 0.f;
            #pragma unroll
            for (int dy=0; dy<2; dy++)
            #pragma unroll
            for (int dx=0; dx<2; dx++) {
                float t = bias;
                #pragma unroll
                for (int ky=0; ky<5; ky++) {
                    const int sl = (2*ph+dy+ky)%6;
                    const uint* rr = dx ? s[sl] : q[sl];
                    t = fdot2(rr[0], wp[ky][0], t);
                    t = fdot2(rr[1], wp[ky][1], t);
                    t = fdot2(rr[2], wp[ky][2], t);
                }
                sum += fast_tanh(t);
            }
            p1o[ph*14] = f16rn(0.25f*sum);
        }
    }
    __syncthreads();

    {
        const int wv = tid >> 6;
        const int l  = tid & 63;
        const int lm = l & 15;
        const int lg = l >> 4;
        uint offr[5][4];
        #pragma unroll
        for (int kk=0; kk<5; kk++) {
            const uint* po = s_offs + kk*16 + lg*4;
            offr[kk][0]=po[0]; offr[kk][1]=po[1]; offr[kk][2]=po[2]; offr[kk][3]=po[3];
        }
        u32x4 afr[5];
        #pragma unroll
        for (int kk=0; kk<5; kk++) {
            const ushort* pa = s_At + (kk*32 + lg*8)*16 + lm;
            #pragma unroll
            for (int p=0; p<4; p++) {
                uint lo = pa[(2*p)*16], hi = pa[(2*p+1)*16];
                afr[kk][p] = pair16(hi, lo);
            }
        }
        const ushort* p1s = (const ushort*)s_p1h;
        for (int tile = wv; tile < 25; tile += 4) {
            const uint base = s_cb[tile*16 + lm];
            f32x4 d = {0.f, 0.f, 0.f, 0.f};
            #pragma unroll
            for (int kk=0; kk<5; kk++) {
                u32x4 b4;
                #pragma unroll
                for (int p=0; p<4; p++) {
                    const uint ow = offr[kk][p];
                    const uint lo = p1s[base + (ow & 0xffffu)];
                    const uint hi = p1s[base + (ow >> 16)];
                    b4[p] = pair16(hi, lo);
                }
                d = __builtin_amdgcn_mfma_f32_16x16x32_f16(
                        __builtin_bit_cast(h8, afr[kk]),
                        __builtin_bit_cast(h8, b4), d, 0, 0, 0);
            }
            const int obase = lg*4;
            const int Q = tile*4 + (lm >> 2);
            const uint qdest = s_qd[Q];
            #pragma unroll
            for (int rg=0; rg<4; rg++) {
                float v = fast_tanh(d[rg] + s_gb16[obase+rg]);
                v += __builtin_bit_cast(float, __builtin_amdgcn_ds_swizzle(__builtin_bit_cast(int, v), 0x041F));
                v += __builtin_bit_cast(float, __builtin_amdgcn_ds_swizzle(__builtin_bit_cast(int, v), 0x081F));
                if ((l & 3) == 0) {
                    ((ushort*)s_u)[qdest + (obase+rg)*25] = f16rn(0.25f*v);
                }
            }
        }
    }
    __syncthreads();

    #pragma unroll
    for (int it=0; it<2; it++) {
        const int id2 = tid + FB_THREADS*it;
        if (id2 < 120*FB_IMGS) {
            const int f = id2 >> 2, img = id2 & 3;
            const uint4* pr4 = (const uint4*)(s_u + img * P2_IMGU);
            float a0=0.f, a1=0.f, a2=0.f, a3=0.f;
            const float4* wr = (const float4*)(c5_w + f*400);
            #pragma unroll 2
            for (int k=0;k<50;k++) {
                float4 wa = wr[2*k], wb = wr[2*k+1];
                uint4 p4 = pr4[k];
                h2 h0 = __builtin_bit_cast(h2, p4.x);
                h2 h1 = __builtin_bit_cast(h2, p4.y);
                h2 hv = __builtin_bit_cast(h2, p4.z);
                h2 h3 = __builtin_bit_cast(h2, p4.w);
                a0 = fmaf((float)h0.x, wa.x, a0); a1 = fmaf((float)h0.y, wa.y, a1);
                a2 = fmaf((float)h1.x, wa.z, a2); a3 = fmaf((float)h1.y, wa.w, a3);
                a0 = fmaf((float)hv.x, wb.x, a0); a1 = fmaf((float)hv.y, wb.y, a1);
                a2 = fmaf((float)h3.x, wb.z, a2); a3 = fmaf((float)h3.y, wb.w, a3);
            }
            const uint bw = s_bh[f >> 1];
            const float bias = (f & 1) ? h2hi(bw) : h2lo(bw);
            ((ushort*)s_c5u)[img*(C5_IMGU*2) + f] =
                f16rn(fast_tanh((a0+a1)+(a2+a3) + bias));
        }
    }
    __syncthreads();

    #pragma unroll
    for (int it=0; it<2; it++) {
        const int id2 = tid + FB_THREADS*it;
        if (id2 < 84*FB_IMGS) {
            const int j = id2 >> 2, img = id2 & 3;
            const uint4* cr4 = (const uint4*)(s_c5u + img * C5_IMGU);
            float a0=0.f, a1=0.f, a2=0.f, a3=0.f;
            const float4* wr = (const float4*)(f6_w + j*120);
            #pragma unroll
            for (int k=0;k<15;k++) {
                float4 wa = wr[2*k], wb = wr[2*k+1];
                uint4 c4 = cr4[k];
                h2 h0 = __builtin_bit_cast(h2, c4.x);
                h2 h1 = __builtin_bit_cast(h2, c4.y);
                h2 hv = __builtin_bit_cast(h2, c4.z);
                h2 h3 = __builtin_bit_cast(h2, c4.w);
                a0 = fmaf((float)h0.x, wa.x, a0); a1 = fmaf((float)h0.y, wa.y, a1);
                a2 = fmaf((float)h1.x, wa.z, a2); a3 = fmaf((float)h1.y, wa.w, a3);
                a0 = fmaf((float)hv.x, wb.x, a0); a1 = fmaf((float)hv.y, wb.y, a1);
                a2 = fmaf((float)h3.x, wb.z, a2); a3 = fmaf((float)h3.y, wb.w, a3);
            }
            const uint bw = s_bh[60 + (j >> 1)];
            const float bias = (j & 1) ? h2hi(bw) : h2lo(bw);
            s_f6[img*84 + j] = fast_tanh((a0+a1)+(a2+a3) + bias);
        }
    }
    __syncthreads();

    if (tid < 10*FB_IMGS) {
        const int j = tid >> 2, img = tid & 3;
        const float* wr = out_w + j*84;
        const float* fr = s_f6 + img*84;
        float a0=0.f,a1=0.f,a2=0.f,a3=0.f;
        #pragma unroll
        for (int k=0;k<84;k+=4) {
            a0=fmaf(wr[k],  fr[k],  a0); a1=fmaf(wr[k+1],fr[k+1],a1);
            a2=fmaf(wr[k+2],fr[k+2],a2); a3=fmaf(wr[k+3],fr[k+3],a3);
        }
        out[((size_t)blk*FB_IMGS + img)*10 + j] = (a0+a1)+(a2+a3) + out_b[j];
    }
}

extern "C" void kernel_launch(void* const* d_in, const int* in_sizes, int n_in,
                              void* d_out, int out_size, void* d_ws, size_t ws_size,
                              hipStream_t stream) {
    const float* x    = (const float*)d_in[0];
    const float* c1w  = (const float*)d_in[1];
    const float* c1b  = (const float*)d_in[2];
    const float* fsw  = (const float*)d_in[3];
    const float* fsb  = (const float*)d_in[4];
    const float* scw  = (const float*)d_in[5];
    const float* scb  = (const float*)d_in[6];
    const float* thw  = (const float*)d_in[7];
    const float* thb  = (const float*)d_in[8];
    const float* fow  = (const float*)d_in[9];
    const float* fob  = (const float*)d_in[10];
    const float* c5w  = (const float*)d_in[11];
    const float* c5b  = (const float*)d_in[12];
    const float* f6w  = (const float*)d_in[13];
    const float* f6b  = (const float*)d_in[14];
    const float* outw = (const float*)d_in[15];
    const float* outb = (const float*)d_in[16];
    float* outp = (float*)d_out;

    const int B = in_sizes[0] / 1024;     // 16384

    if (ws_size >= (size_t)WS_NEED_BYTES) {
        ushort* wsh = (ushort*)d_ws;
        cvt_tabs<<<208, 256, 0, stream>>>(c1w, c1b, fsw, fsb, scw, scb, thw, thb,
                                          fow, fob, c5w, c5b, f6w, f6b, wsh);
        lenet_ws<<<B / IMGS, THREADS, 0, stream>>>(x, outw, outb, wsh, outp);
    } else {
        lenet_nows<<<B / FB_IMGS, FB_THREADS, 0, stream>>>(
            x, c1w, c1b, fsw, fsb, scw, scb, thw, thb, fow, fob,
            c5w, c5b, f6w, f6b, outw, outb, outp);
    }
}

// Round 19
// 116.510 us; speedup vs baseline: 2.1547x; 1.2117x over previous
//
#include <hip/hip_runtime.h>
#include <hip/hip_fp16.h>

#define THREADS 512
#define IMGS 8

#define O_C1B 0
#define O_GB  6

// p1 fp16 layout (uint units): ch stride mod32=9, img stride mod32=22
#define P1_CHU 105
#define P1_IMGU 630
// p2 fp16: 200 uints/img (400 halves), 16B-aligned
#define P2_IMGU 200
// c5 fp16: 60 uints/img (120 halves), 16B-aligned
#define C5_IMGU 60

// d_ws layout (half-index):
#define WS_C5K   416
#define WS_F6    53248
#define WS_F6K   128
#define WS_ATP_H 65536
#define WS_CB    68096
#define WS_QD    68896
#define WS_OFFS_H 69096
#define WS_SB_H  69256
#define WS_NEED_BYTES 139408

typedef _Float16 h2 __attribute__((ext_vector_type(2)));
typedef _Float16 h8 __attribute__((ext_vector_type(8)));
typedef float    f32x4 __attribute__((ext_vector_type(4)));
typedef uint     u32x4 __attribute__((ext_vector_type(4)));

__device__ __forceinline__ float fdot2(uint a, uint b, float c) {
    return __builtin_amdgcn_fdot2(__builtin_bit_cast(h2, a), __builtin_bit_cast(h2, b), c, false);
}
__device__ __forceinline__ uint pkh2(float a, float b) {
    return __builtin_bit_cast(uint, __builtin_amdgcn_cvt_pkrtz(a, b));
}
__device__ __forceinline__ ushort f16rn(float a) {
    _Float16 h = (_Float16)a;
    return __builtin_bit_cast(ushort, h);
}
__device__ __forceinline__ float h2lo(uint w){ return (float)__builtin_bit_cast(h2, w).x; }
__device__ __forceinline__ float h2hi(uint w){ return (float)__builtin_bit_cast(h2, w).y; }

__device__ __forceinline__ uint pair16(uint hi, uint lo) {
    return __builtin_amdgcn_perm(hi, lo, 0x05040100u);
}
__device__ __forceinline__ uint funnel16(uint hi, uint lo) {
    return __builtin_amdgcn_alignbit(hi, lo, 16);
}

// tanh(v) = 1 - 2/(exp2(v*2*log2e)+1): 5 VALU (mul, exp2, add, rcp, fma)
// deterministic per-lane math; numerics validated end-to-end in R18 first-call (absmax 3.9e-3)
__device__ __forceinline__ float fast_tanh(float v) {
    float e = __builtin_amdgcn_exp2f(v * 2.885390081777927f);
    return fmaf(-2.f, __builtin_amdgcn_rcpf(e + 1.f), 1.f);
}

__device__ __forceinline__ void ld_row(const uint* p, uint* q, uint* s) {
    uint a = p[0], b = p[1], c = p[2];
    q[0] = a; q[1] = b; q[2] = c;
    s[0] = funnel16(b, a);
    s[1] = funnel16(c, b);
    s[2] = c >> 16;
}

// grouped-C3 A value: weight of output o at flat tap t (0..159), 0 if outside group
__device__ __forceinline__ float atval(int t, int o,
                                       const float* fsw, const float* scw,
                                       const float* thw, const float* fow) {
    float v = 0.f;
    if (t < 150) {
        const int ch = t / 25, tap = t % 25;
        if (o < 6)       { int d = ch - o;      if (d < 0) d += 6; if (d < 3) v = fsw[d*25 + tap]; }
        else if (o < 12) { int d = ch - (o-6);  if (d < 0) d += 6; if (d < 4) v = scw[d*25 + tap]; }
        else if (o < 15) { int d = ch - (o-12); if (d < 0) d += 6;
                           int j = (d<2) ? d : (d==3 ? 2 : (d==4 ? 3 : -1));
                           if (j >= 0) v = thw[j*25 + tap]; }
        else             v = fow[ch*25 + tap];
    }
    return v;
}

// pre-kernel: all input-independent tables -> d_ws
__global__ __launch_bounds__(256)
void cvt_tabs(const float* __restrict__ c1w, const float* __restrict__ c1b,
              const float* __restrict__ fsw, const float* __restrict__ fsb,
              const float* __restrict__ scw, const float* __restrict__ scb,
              const float* __restrict__ thw, const float* __restrict__ thb,
              const float* __restrict__ fow, const float* __restrict__ fob,
              const float* __restrict__ c5w, const float* __restrict__ c5b,
              const float* __restrict__ f6w, const float* __restrict__ f6b,
              ushort* __restrict__ ws) {
    const int i = blockIdx.x * 256 + threadIdx.x;
    if (i < 53248) {
        int r = i / WS_C5K, k = i % WS_C5K;
        float v = (r < 120 && k < 400) ? c5w[r*400 + k] : 0.f;
        ws[i] = f16rn(v);
    }
    if (i < 12288) {
        int r = i / WS_F6K, k = i % WS_F6K;
        float v = (r < 84 && k < 120) ? f6w[r*120 + k] : 0.f;
        ws[WS_F6 + i] = f16rn(v);
    }
    if (blockIdx.x == 0) {
        const int t = threadIdx.x;
        uint* wAtp = (uint*)(ws + WS_ATP_H);
        for (int idx = t; idx < 1280; idx += 256) {
            const int m = idx & 15, p = (idx >> 4) & 3, lg = (idx >> 6) & 3, kk = idx >> 8;
            const int tt = kk*32 + lg*8 + 2*p;
            wAtp[idx] = pkh2(atval(tt,   m, fsw, scw, thw, fow),
                             atval(tt+1, m, fsw, scw, thw, fow));
        }
        // cb: col -> p1 half-base (800 cols: 8 imgs x 25 quads x 4 corners)
        for (int col = t; col < 800; col += 256) {
            const int Q = col >> 2, corner = col & 3;
            const int img = Q / 25, q = Q % 25;
            const int qh = q / 5, qw = q % 5;
            const int h = 2*qh + (corner & 1);
            const int w = 2*qw + (corner >> 1);
            ws[WS_CB + col] = (ushort)(img*(P1_IMGU*2) + h*14 + w);
        }
        // qd: quad -> p2 dest half-base (200 quads)
        for (int Q = t; Q < 200; Q += 256)
            ws[WS_QD + Q] = (ushort)((Q/25)*(P2_IMGU*2) + (Q%25));
        // offs: packed tap offsets
        uint* wo = (uint*)(ws + WS_OFFS_H);
        for (int i2 = t; i2 < 80; i2 += 256) {
            uint o2[2];
            #pragma unroll
            for (int z=0; z<2; z++) {
                const int tt = 2*i2 + z;
                if (tt < 150) {
                    const int ch = tt/25, rem = tt%25, ky = rem/5, kx = rem%5;
                    o2[z] = (uint)(ch*(P1_CHU*2) + ky*14 + kx);
                } else o2[z] = 0u;
            }
            wo[i2] = o2[0] | (o2[1] << 16);
        }
        // small blob: whu[0..95] | w[96..105] | gb16[106..121] | bh[122..223]
        uint* sb = (uint*)(ws + WS_SB_H);
        if (t < 6) {
            const float* src = c1w + t*25;
            uint* dst = sb + t*16;
            #pragma unroll
            for (int ky=0; ky<5; ky++) {
                dst[ky*3+0] = pkh2(src[ky*5+0], src[ky*5+1]);
                dst[ky*3+1] = pkh2(src[ky*5+2], src[ky*5+3]);
                dst[ky*3+2] = pkh2(src[ky*5+4], 0.f);
            }
            dst[15] = 0u;
        }
        float* wf = (float*)(sb + 96);
        if (t < 6) wf[O_C1B + t] = c1b[t];
        if (t == 0){ wf[O_GB+0]=fsb[0]; wf[O_GB+1]=scb[0]; wf[O_GB+2]=thb[0]; wf[O_GB+3]=fob[0]; }
        float* gbf = (float*)(sb + 106);
        if (t < 16) gbf[t] = t<6 ? fsb[0] : (t<12 ? scb[0] : (t<15 ? thb[0] : fob[0]));
        if (t < 60) sb[122 + t]      = pkh2(c5b[2*t], c5b[2*t+1]);
        if (t < 42) sb[122 + 60 + t] = pkh2(f6b[2*t], f6b[2*t+1]);
    }
}

// ============ main fused kernel (requires prepared ws) — IMGS=8, 512 thr ============
__global__ __launch_bounds__(THREADS)
void lenet_ws(const float* __restrict__ x,
              const float* __restrict__ out_w, const float* __restrict__ out_b,
              const ushort* __restrict__ wsh,
              float* __restrict__ out)
{
    __shared__ uint s_p1h[IMGS * P1_IMGU];          // 20160 B; f6 fp32 aliases later
    __shared__ __align__(16) uint s_tbl[224];       // 896 B: whu | w | gb16 | bh
    __shared__ uint s_u[IMGS * 512];                // 16384 B: x fp16 / p2h+c5h
    uint*  s_whu  = s_tbl;
    float* s_w    = (float*)(s_tbl + 96);
    float* s_gb16 = (float*)(s_tbl + 106);
    uint*  s_bh   = s_tbl + 122;
    uint*  s_xh   = s_u;
    uint*  s_c5u  = s_u + IMGS * P2_IMGU;           // uints 1600..2079
    float* s_f6   = (float*)s_p1h;

    const int tid = threadIdx.x;
    const int blk = blockIdx.x;

    // ---- stage 0: copy small blob (56 x uint4) ----
    if (tid < 56) {
        ((uint4*)s_tbl)[tid] = ((const uint4*)(wsh + WS_SB_H))[tid];
    }

    // ---- stage 1: x -> LDS as fp16 pairs ----
    {
        const float4* xg = (const float4*)(x + (size_t)blk*(IMGS*1024));
        uint2* sx = (uint2*)s_u;
        #pragma unroll
        for (int i=0;i<(IMGS*1024/4)/THREADS;i++) {
            float4 v = xg[tid + i*THREADS];
            sx[tid + i*THREADS] = make_uint2(pkh2(v.x,v.y), pkh2(v.z,v.w));
        }
    }
    __syncthreads();

    // ---- stage 2: conv1 + tanh + 2x2 avgpool -> s_p1h (fp16) ----
    for (int idx=tid; idx<IMGS*84; idx+=THREADS) {
        const int img = idx/84, r2 = idx%84, c = r2/14, pw = r2%14;
        const uint* xim = s_xh + img*512 + pw;
        uint wp[5][3];
        #pragma unroll
        for (int k=0;k<15;k++) ((uint*)wp)[k] = s_whu[c*16 + k];
        const float bias = s_w[O_C1B + c];
        uint q[6][3], s[6][3];
        #pragma unroll
        for (int r=0;r<4;r++) ld_row(xim + r*16, q[r], s[r]);
        ushort* p1o = (ushort*)s_p1h + img*(P1_IMGU*2) + c*(P1_CHU*2) + pw;
        #pragma unroll
        for (int ph=0; ph<14; ph++) {
            ld_row(xim + (2*ph+4)*16, q[(2*ph+4)%6], s[(2*ph+4)%6]);
            ld_row(xim + (2*ph+5)*16, q[(2*ph+5)%6], s[(2*ph+5)%6]);
            float sum = 0.f;
            #pragma unroll
            for (int dy=0; dy<2; dy++)
            #pragma unroll
            for (int dx=0; dx<2; dx++) {
                float t = bias;
                #pragma unroll
                for (int ky=0; ky<5; ky++) {
                    const int sl = (2*ph+dy+ky)%6;
                    const uint* rr = dx ? s[sl] : q[sl];
                    t = fdot2(rr[0], wp[ky][0], t);
                    t = fdot2(rr[1], wp[ky][1], t);
                    t = fdot2(rr[2], wp[ky][2], t);
                }
                sum += fast_tanh(t);
            }
            p1o[ph*14] = f16rn(0.25f*sum);
        }
    }
    __syncthreads();

    // ---- stage 3: grouped C3 as MFMA GEMM (50 N-tiles over 8 waves) ----
    {
        const int wv = tid >> 6;
        const int l  = tid & 63;
        const int lm = l & 15;
        const int lg = l >> 4;
        const uint*   gAtp  = (const uint*)(wsh + WS_ATP_H);
        const uint*   goffs = (const uint*)(wsh + WS_OFFS_H);
        const ushort* gcb   = wsh + WS_CB;
        const ushort* gqd   = wsh + WS_QD;
        uint offr[5][4];
        #pragma unroll
        for (int kk=0; kk<5; kk++) {
            #pragma unroll
            for (int j=0; j<4; j++) offr[kk][j] = goffs[kk*16 + lg*4 + j];
        }
        u32x4 afr[5];
        #pragma unroll
        for (int kk=0; kk<5; kk++) {
            #pragma unroll
            for (int p=0; p<4; p++)
                afr[kk][p] = gAtp[((kk*4 + lg)*4 + p)*16 + lm];
        }
        const ushort* p1s = (const ushort*)s_p1h;
        for (int tile = wv; tile < 50; tile += 8) {
            const uint base = gcb[tile*16 + lm];
            f32x4 d = {0.f, 0.f, 0.f, 0.f};
            #pragma unroll
            for (int kk=0; kk<5; kk++) {
                u32x4 b4;
                #pragma unroll
                for (int p=0; p<4; p++) {
                    const uint ow = offr[kk][p];
                    const uint lo = p1s[base + (ow & 0xffffu)];
                    const uint hi = p1s[base + (ow >> 16)];
                    b4[p] = pair16(hi, lo);
                }
                d = __builtin_amdgcn_mfma_f32_16x16x32_f16(
                        __builtin_bit_cast(h8, afr[kk]),
                        __builtin_bit_cast(h8, b4), d, 0, 0, 0);
            }
            const int obase = lg*4;
            const int Q = tile*4 + (lm >> 2);
            const uint qdest = gqd[Q];
            #pragma unroll
            for (int rg=0; rg<4; rg++) {
                float v = fast_tanh(d[rg] + s_gb16[obase+rg]);
                v += __builtin_bit_cast(float, __builtin_amdgcn_ds_swizzle(__builtin_bit_cast(int, v), 0x041F));
                v += __builtin_bit_cast(float, __builtin_amdgcn_ds_swizzle(__builtin_bit_cast(int, v), 0x081F));
                if ((l & 3) == 0) {
                    ((ushort*)s_u)[qdest + (obase+rg)*25] = f16rn(0.25f*v);
                }
            }
        }
    }
    __syncthreads();

    // ---- stage 4: conv5 as MFMA GEMM: D[120 f][8 img] — 8 M-tiles over 8 waves ----
    {
        const int wv = tid >> 6;
        const int l  = tid & 63;
        const int lm = l & 15;
        const int lg = l >> 4;
        const ushort* p2s = (const ushort*)s_u + (lm & 7)*(P2_IMGU*2) + lg*8;
        const int mt = wv;                     // M-tile 0..7
        const ushort* arow = wsh + (mt*16 + lm)*WS_C5K + lg*8;
        f32x4 d = {0.f, 0.f, 0.f, 0.f};
        #pragma unroll
        for (int ks=0; ks<13; ks++) {
            u32x4 a4 = *(const u32x4*)(arow + ks*32);
            u32x4 b4 = *(const u32x4*)(p2s + ks*32);
            d = __builtin_amdgcn_mfma_f32_16x16x32_f16(
                    __builtin_bit_cast(h8, a4),
                    __builtin_bit_cast(h8, b4), d, 0, 0, 0);
        }
        if (lm < 8) {
            #pragma unroll
            for (int rg=0; rg<4; rg++) {
                const int f = mt*16 + lg*4 + rg;
                if (f < 120) {
                    const uint bw = s_bh[f >> 1];
                    const float bias = (f & 1) ? h2hi(bw) : h2lo(bw);
                    ((ushort*)s_c5u)[lm*(C5_IMGU*2) + f] = f16rn(fast_tanh(d[rg] + bias));
                }
            }
        }
    }
    __syncthreads();

    // ---- stage 5: f6 as MFMA GEMM: D[84 j][8 img] — 6 M-tiles, waves 0-5 ----
    {
        const int wv = tid >> 6;
        const int l  = tid & 63;
        const int lm = l & 15;
        const int lg = l >> 4;
        if (wv < 6) {
            const ushort* c5s = (const ushort*)s_c5u + (lm & 7)*(C5_IMGU*2) + lg*8;
            const int mt = wv;
            const ushort* arow = wsh + WS_F6 + (mt*16 + lm)*WS_F6K + lg*8;
            f32x4 d = {0.f, 0.f, 0.f, 0.f};
            #pragma unroll
            for (int ks=0; ks<4; ks++) {
                u32x4 a4 = *(const u32x4*)(arow + ks*32);
                u32x4 b4 = *(const u32x4*)(c5s + ks*32);
                d = __builtin_amdgcn_mfma_f32_16x16x32_f16(
                        __builtin_bit_cast(h8, a4),
                        __builtin_bit_cast(h8, b4), d, 0, 0, 0);
            }
            if (lm < 8) {
                #pragma unroll
                for (int rg=0; rg<4; rg++) {
                    const int j = mt*16 + lg*4 + rg;
                    if (j < 84) {
                        const uint bw = s_bh[60 + (j >> 1)];
                        const float bias = (j & 1) ? h2hi(bw) : h2lo(bw);
                        s_f6[lm*84 + j] = fast_tanh(d[rg] + bias);
                    }
                }
            }
        }
    }
    __syncthreads();

    // ---- stage 6: out (10x84) -> global ----
    if (tid < 10*IMGS) {
        const int j = tid >> 3, img = tid & 7;
        const float* wr = out_w + j*84;
        const float* fr = s_f6 + img*84;
        float a0=0.f,a1=0.f,a2=0.f,a3=0.f;
        #pragma unroll
        for (int k=0;k<84;k+=4) {
            a0=fmaf(wr[k],  fr[k],  a0); a1=fmaf(wr[k+1],fr[k+1],a1);
            a2=fmaf(wr[k+2],fr[k+2],a2); a3=fmaf(wr[k+3],fr[k+3],a3);
        }
        out[((size_t)blk*IMGS + img)*10 + j] = (a0+a1)+(a2+a3) + out_b[j];
    }
}

// ============ self-contained fallback (no ws) — R15 structure, IMGS=4 ============
#define FB_IMGS 4
#define FB_THREADS 256
__global__ __launch_bounds__(FB_THREADS)
void lenet_nows(const float* __restrict__ x,
                const float* __restrict__ c1_w, const float* __restrict__ c1_b,
                const float* __restrict__ fs_w, const float* __restrict__ fs_b,
                const float* __restrict__ sc_w, const float* __restrict__ sc_b,
                const float* __restrict__ th_w, const float* __restrict__ th_b,
                const float* __restrict__ fo_w, const float* __restrict__ fo_b,
                const float* __restrict__ c5_w, const float* __restrict__ c5_b,
                const float* __restrict__ f6_w, const float* __restrict__ f6_b,
                const float* __restrict__ out_w, const float* __restrict__ out_b,
                float* __restrict__ out)
{
    __shared__ uint   s_p1h[FB_IMGS * P1_IMGU];
    __shared__ uint   s_whu[6 * 16];
    __shared__ float  s_w[10];
    __shared__ float  s_gb16[16];
    __shared__ uint   s_bh[102];
    __shared__ ushort s_At[160*16];
    __shared__ ushort s_cb[400];
    __shared__ uint   s_offs[80];
    __shared__ ushort s_qd[100];
    __shared__ uint   s_u[FB_IMGS * 512];
    uint*  s_xh  = s_u;
    uint*  s_c5u = s_u + FB_IMGS * P2_IMGU;
    float* s_f6  = (float*)s_p1h;

    const int tid = threadIdx.x;
    const int blk = blockIdx.x;

    if (tid < 6)  s_w[O_C1B + tid] = c1_b[tid];
    if (tid == 0){ s_w[O_GB+0]=fs_b[0]; s_w[O_GB+1]=sc_b[0]; s_w[O_GB+2]=th_b[0]; s_w[O_GB+3]=fo_b[0]; }
    if (tid < 16) s_gb16[tid] = tid<6 ? fs_b[0] : (tid<12 ? sc_b[0] : (tid<15 ? th_b[0] : fo_b[0]));
    if (tid < 60) s_bh[tid]      = pkh2(c5_b[2*tid], c5_b[2*tid+1]);
    if (tid < 42) s_bh[60 + tid] = pkh2(f6_b[2*tid], f6_b[2*tid+1]);

    if (tid < 6) {
        const float* src = c1_w + tid*25;
        uint* dst = s_whu + tid*16;
        #pragma unroll
        for (int ky=0; ky<5; ky++) {
            dst[ky*3+0] = pkh2(src[ky*5+0], src[ky*5+1]);
            dst[ky*3+1] = pkh2(src[ky*5+2], src[ky*5+3]);
            dst[ky*3+2] = pkh2(src[ky*5+4], 0.f);
        }
    }

    for (int e = tid; e < 2560; e += FB_THREADS) {
        const int t = e >> 4, o = e & 15;
        s_At[t*16 + o] = f16rn(atval(t, o, fs_w, sc_w, th_w, fo_w));
    }
    for (int col = tid; col < 400; col += FB_THREADS) {
        const int Q = col >> 2, corner = col & 3;
        const int img = Q / 25, q = Q % 25;
        const int qh = q / 5, qw = q % 5;
        const int h = 2*qh + (corner & 1);
        const int w = 2*qw + (corner >> 1);
        s_cb[col] = (ushort)(img*(P1_IMGU*2) + h*14 + w);
    }
    for (int i = tid; i < 80; i += FB_THREADS) {
        uint o2[2];
        #pragma unroll
        for (int z=0; z<2; z++) {
            const int t = 2*i + z;
            if (t < 150) {
                const int ch = t/25, rem = t%25, ky = rem/5, kx = rem%5;
                o2[z] = (uint)(ch*(P1_CHU*2) + ky*14 + kx);
            } else o2[z] = 0u;
        }
        s_offs[i] = o2[0] | (o2[1] << 16);
    }
    for (int Q = tid; Q < 100; Q += FB_THREADS) {
        s_qd[Q] = (ushort)((Q/25)*(P2_IMGU*2) + (Q%25));
    }

    {
        const float4* xg = (const float4*)(x + (size_t)blk*(FB_IMGS*1024));
        uint2* sx = (uint2*)s_u;
        #pragma unroll
        for (int i=0;i<(FB_IMGS*1024/4)/FB_THREADS;i++) {
            float4 v = xg[tid + i*FB_THREADS];
            sx[tid + i*FB_THREADS] = make_uint2(pkh2(v.x,v.y), pkh2(v.z,v.w));
        }
    }
    __syncthreads();

    for (int idx=tid; idx<FB_IMGS*84; idx+=FB_THREADS) {
        const int img = idx/84, r2 = idx%84, c = r2/14, pw = r2%14;
        const uint* xim = s_xh + img*512 + pw;
        uint wp[5][3];
        #pragma unroll
        for (int k=0;k<15;k++) ((uint*)wp)[k] = s_whu[c*16 + k];
        const float bias = s_w[O_C1B + c];
        uint q[6][3], s[6][3];
        #pragma unroll
        for (int r=0;r<4;r++) ld_row(xim + r*16, q[r], s[r]);
        ushort* p1o = (ushort*)s_p1h + img*(P1_IMGU*2) + c*(P1_CHU*2) + pw;
        #pragma unroll
        for (int ph=0; ph<14; ph++) {
            ld_row(xim + (2*ph+4)*16, q[(2*ph+4)%6], s[(2*ph+4)%6]);
            ld_row(xim + (2*ph+5)*16, q[(2*ph+5)%6], s[(2*ph+5)%6]);
            float sum = 0.f;
            #pragma unroll
            for (int dy=0; dy<2; dy++)
            #pragma unroll
            for (int dx=0; dx<2; dx++) {
                float t = bias;
                #pragma unroll
                for (int ky=0; ky<5; ky++) {
                    const int sl = (2*ph+dy+ky)%6;
                    const uint* rr = dx ? s[sl] : q[sl];
                    t = fdot2(rr[0], wp[ky][0], t);
                    t = fdot2(rr[1], wp[ky][1], t);
                    t = fdot2(rr[2], wp[ky][2], t);
                }
                sum += fast_tanh(t);
            }
            p1o[ph*14] = f16rn(0.25f*sum);
        }
    }
    __syncthreads();

    {
        const int wv = tid >> 6;
        const int l  = tid & 63;
        const int lm = l & 15;
        const int lg = l >> 4;
        uint offr[5][4];
        #pragma unroll
        for (int kk=0; kk<5; kk++) {
            const uint* po = s_offs + kk*16 + lg*4;
            offr[kk][0]=po[0]; offr[kk][1]=po[1]; offr[kk][2]=po[2]; offr[kk][3]=po[3];
        }
        u32x4 afr[5];
        #pragma unroll
        for (int kk=0; kk<5; kk++) {
            const ushort* pa = s_At + (kk*32 + lg*8)*16 + lm;
            #pragma unroll
            for (int p=0; p<4; p++) {
                uint lo = pa[(2*p)*16], hi = pa[(2*p+1)*16];
                afr[kk][p] = pair16(hi, lo);
            }
        }
        const ushort* p1s = (const ushort*)s_p1h;
        for (int tile = wv; tile < 25; tile += 4) {
            const uint base = s_cb[tile*16 + lm];
            f32x4 d = {0.f, 0.f, 0.f, 0.f};
            #pragma unroll
            for (int kk=0; kk<5; kk++) {
                u32x4 b4;
                #pragma unroll
                for (int p=0; p<4; p++) {
                    const uint ow = offr[kk][p];
                    const uint lo = p1s[base + (ow & 0xffffu)];
                    const uint hi = p1s[base + (ow >> 16)];
                    b4[p] = pair16(hi, lo);
                }
                d = __builtin_amdgcn_mfma_f32_16x16x32_f16(
                        __builtin_bit_cast(h8, afr[kk]),
                        __builtin_bit_cast(h8, b4), d, 0, 0, 0);
            }
            const int obase = lg*4;
            const int Q = tile*4 + (lm >> 2);
            const uint qdest = s_qd[Q];
            #pragma unroll
            for (int rg=0; rg<4; rg++) {
                float v = fast_tanh(d[rg] + s_gb16[obase+rg]);
                v += __builtin_bit_cast(float, __builtin_amdgcn_ds_swizzle(__builtin_bit_cast(int, v), 0x041F));
                v += __builtin_bit_cast(float, __builtin_amdgcn_ds_swizzle(__builtin_bit_cast(int, v), 0x081F));
                if ((l & 3) == 0) {
                    ((ushort*)s_u)[qdest + (obase+rg)*25] = f16rn(0.25f*v);
                }
            }
        }
    }
    __syncthreads();

    #pragma unroll
    for (int it=0; it<2; it++) {
        const int id2 = tid + FB_THREADS*it;
        if (id2 < 120*FB_IMGS) {
            const int f = id2 >> 2, img = id2 & 3;
            const uint4* pr4 = (const uint4*)(s_u + img * P2_IMGU);
            float a0=0.f, a1=0.f, a2=0.f, a3=0.f;
            const float4* wr = (const float4*)(c5_w + f*400);
            #pragma unroll 2
            for (int k=0;k<50;k++) {
                float4 wa = wr[2*k], wb = wr[2*k+1];
                uint4 p4 = pr4[k];
                h2 h0 = __builtin_bit_cast(h2, p4.x);
                h2 h1 = __builtin_bit_cast(h2, p4.y);
                h2 hv = __builtin_bit_cast(h2, p4.z);
                h2 h3 = __builtin_bit_cast(h2, p4.w);
                a0 = fmaf((float)h0.x, wa.x, a0); a1 = fmaf((float)h0.y, wa.y, a1);
                a2 = fmaf((float)h1.x, wa.z, a2); a3 = fmaf((float)h1.y, wa.w, a3);
                a0 = fmaf((float)hv.x, wb.x, a0); a1 = fmaf((float)hv.y, wb.y, a1);
                a2 = fmaf((float)h3.x, wb.z, a2); a3 = fmaf((float)h3.y, wb.w, a3);
            }
            const uint bw = s_bh[f >> 1];
            const float bias = (f & 1) ? h2hi(bw) : h2lo(bw);
            ((ushort*)s_c5u)[img*(C5_IMGU*2) + f] =
                f16rn(fast_tanh((a0+a1)+(a2+a3) + bias));
        }
    }
    __syncthreads();

    #pragma unroll
    for (int it=0; it<2; it++) {
        const int id2 = tid + FB_THREADS*it;
        if (id2 < 84*FB_IMGS) {
            const int j = id2 >> 2, img = id2 & 3;
            const uint4* cr4 = (const uint4*)(s_c5u + img * C5_IMGU);
            float a0=0.f, a1=0.f, a2=0.f, a3=0.f;
            const float4* wr = (const float4*)(f6_w + j*120);
            #pragma unroll
            for (int k=0;k<15;k++) {
                float4 wa = wr[2*k], wb = wr[2*k+1];
                uint4 c4 = cr4[k];
                h2 h0 = __builtin_bit_cast(h2, c4.x);
                h2 h1 = __builtin_bit_cast(h2, c4.y);
                h2 hv = __builtin_bit_cast(h2, c4.z);
                h2 h3 = __builtin_bit_cast(h2, c4.w);
                a0 = fmaf((float)h0.x, wa.x, a0); a1 = fmaf((float)h0.y, wa.y, a1);
                a2 = fmaf((float)h1.x, wa.z, a2); a3 = fmaf((float)h1.y, wa.w, a3);
                a0 = fmaf((float)hv.x, wb.x, a0); a1 = fmaf((float)hv.y, wb.y, a1);
                a2 = fmaf((float)h3.x, wb.z, a2); a3 = fmaf((float)h3.y, wb.w, a3);
            }
            const uint bw = s_bh[60 + (j >> 1)];
            const float bias = (j & 1) ? h2hi(bw) : h2lo(bw);
            s_f6[img*84 + j] = fast_tanh((a0+a1)+(a2+a3) + bias);
        }
    }
    __syncthreads();

    if (tid < 10*FB_IMGS) {
        const int j = tid >> 2, img = tid & 3;
        const float* wr = out_w + j*84;
        const float* fr = s_f6 + img*84;
        float a0=0.f,a1=0.f,a2=0.f,a3=0.f;
        #pragma unroll
        for (int k=0;k<84;k+=4) {
            a0=fmaf(wr[k],  fr[k],  a0); a1=fmaf(wr[k+1],fr[k+1],a1);
            a2=fmaf(wr[k+2],fr[k+2],a2); a3=fmaf(wr[k+3],fr[k+3],a3);
        }
        out[((size_t)blk*FB_IMGS + img)*10 + j] = (a0+a1)+(a2+a3) + out_b[j];
    }
}

extern "C" void kernel_launch(void* const* d_in, const int* in_sizes, int n_in,
                              void* d_out, int out_size, void* d_ws, size_t ws_size,
                              hipStream_t stream) {
    const float* x    = (const float*)d_in[0];
    const float* c1w  = (const float*)d_in[1];
    const float* c1b  = (const float*)d_in[2];
    const float* fsw  = (const float*)d_in[3];
    const float* fsb  = (const float*)d_in[4];
    const float* scw  = (const float*)d_in[5];
    const float* scb  = (const float*)d_in[6];
    const float* thw  = (const float*)d_in[7];
    const float* thb  = (const float*)d_in[8];
    const float* fow  = (const float*)d_in[9];
    const float* fob  = (const float*)d_in[10];
    const float* c5w  = (const float*)d_in[11];
    const float* c5b  = (const float*)d_in[12];
    const float* f6w  = (const float*)d_in[13];
    const float* f6b  = (const float*)d_in[14];
    const float* outw = (const float*)d_in[15];
    const float* outb = (const float*)d_in[16];
    float* outp = (float*)d_out;

    const int B = in_sizes[0] / 1024;     // 16384

    if (ws_size >= (size_t)WS_NEED_BYTES) {
        ushort* wsh = (ushort*)d_ws;
        cvt_tabs<<<208, 256, 0, stream>>>(c1w, c1b, fsw, fsb, scw, scb, thw, thb,
                                          fow, fob, c5w, c5b, f6w, f6b, wsh);
        lenet_ws<<<B / IMGS, THREADS, 0, stream>>>(x, outw, outb, wsh, outp);
    } else {
        lenet_nows<<<B / FB_IMGS, FB_THREADS, 0, stream>>>(
            x, c1w, c1b, fsw, fsb, scw, scb, thw, thb, fow, fob,
            c5w, c5b, f6w, f6b, outw, outb, outp);
    }
}